// Round 1
// baseline (1344.413 us; speedup 1.0000x reference)
//
#include <hip/hip_runtime.h>
#include <hip/hip_bf16.h>

#define BATCH 8
#define LTOK 1280
#define DIMC 192
#define HEADS 6
#define KD 32
#define HID 768
#define NROWS (BATCH*LTOK)   // 10240

// ---------------- LayerNorm: 4 rows/block, 64 lanes per row ----------------
__global__ __launch_bounds__(256) void ln_kernel(const float* __restrict__ x,
                                                 const float* __restrict__ g,
                                                 const float* __restrict__ b,
                                                 float* __restrict__ y) {
    int row = blockIdx.x * 4 + (threadIdx.x >> 6);
    int lane = threadIdx.x & 63;
    const float* xr = x + (size_t)row * DIMC;
    float v0 = xr[lane], v1 = xr[lane + 64], v2 = xr[lane + 128];
    float s = v0 + v1 + v2;
    float ss = v0 * v0 + v1 * v1 + v2 * v2;
    #pragma unroll
    for (int off = 32; off; off >>= 1) {
        s  += __shfl_xor(s, off);
        ss += __shfl_xor(ss, off);
    }
    float mu  = s * (1.0f / DIMC);
    float var = ss * (1.0f / DIMC) - mu * mu;
    float inv = rsqrtf(var + 1e-5f);
    float* yr = y + (size_t)row * DIMC;
    yr[lane]       = (v0 - mu) * inv * g[lane]       + b[lane];
    yr[lane + 64]  = (v1 - mu) * inv * g[lane + 64]  + b[lane + 64];
    yr[lane + 128] = (v2 - mu) * inv * g[lane + 128] + b[lane + 128];
}

// ---------------- Generic fp32 GEMM: C = act(A@W + bias) (+R) --------------
// BM=BN=64, BK=16, 256 threads, 4x4 per thread. M%64==0, N%64==0, K%16==0.
template<int ACT, int RES>
__global__ __launch_bounds__(256) void gemm_kernel(const float* __restrict__ A,
                                                   const float* __restrict__ W,
                                                   const float* __restrict__ bias,
                                                   const float* __restrict__ R,
                                                   float* __restrict__ C,
                                                   int M, int N, int K) {
    __shared__ float As[64][17];
    __shared__ float Ws[16][64];
    int tid = threadIdx.x;
    int tx = tid & 15, ty = tid >> 4;
    int m0 = blockIdx.y * 64, n0 = blockIdx.x * 64;
    float acc[4][4] = {};
    for (int k0 = 0; k0 < K; k0 += 16) {
        #pragma unroll
        for (int i = 0; i < 4; ++i) {
            int e = tid + i * 256;
            int ar = e >> 4, ac = e & 15;
            As[ar][ac] = A[(size_t)(m0 + ar) * K + k0 + ac];
        }
        #pragma unroll
        for (int i = 0; i < 4; ++i) {
            int e = tid + i * 256;
            int kr = e >> 6, nc = e & 63;
            Ws[kr][nc] = W[(size_t)(k0 + kr) * N + n0 + nc];
        }
        __syncthreads();
        #pragma unroll
        for (int kk = 0; kk < 16; ++kk) {
            float a0 = As[ty * 4 + 0][kk];
            float a1 = As[ty * 4 + 1][kk];
            float a2 = As[ty * 4 + 2][kk];
            float a3 = As[ty * 4 + 3][kk];
            float4 wv = *(const float4*)&Ws[kk][tx * 4];
            float w[4] = {wv.x, wv.y, wv.z, wv.w};
            float a[4] = {a0, a1, a2, a3};
            #pragma unroll
            for (int i = 0; i < 4; ++i)
                #pragma unroll
                for (int j = 0; j < 4; ++j)
                    acc[i][j] += a[i] * w[j];
        }
        __syncthreads();
    }
    #pragma unroll
    for (int i = 0; i < 4; ++i) {
        int row = m0 + ty * 4 + i;
        #pragma unroll
        for (int j = 0; j < 4; ++j) {
            int col = n0 + tx * 4 + j;
            float v = acc[i][j] + bias[col];
            if (ACT == 1) v = 0.5f * v * (1.0f + erff(v * 0.70710678118654752f));
            if (RES) v += R[(size_t)row * N + col];
            C[(size_t)row * N + col] = v;
        }
    }
}

// ---------------- Attention: flash-style, block = (h, 16-row q-tile) -------
#define QT 16
#define MT 64
__global__ __launch_bounds__(256) void attn_kernel(const float* __restrict__ qkv,
                                                   const int* __restrict__ bidx,
                                                   const float* __restrict__ table,
                                                   int n_off,
                                                   float* __restrict__ o) {
    int h  = blockIdx.y;
    int n0 = blockIdx.x * QT;
    int tid = threadIdx.x;
    int r  = tid >> 4;           // 0..15 (q row in tile)
    int c4 = (tid & 15) * 4;     // 0..60 (4 score cols)
    int d0 = (tid & 15) * 2;     // 2 output dims

    __shared__ float k_t[MT][33];
    __shared__ float v_t[MT][33];
    __shared__ float s_t[QT][65];
    __shared__ float red[QT][17];
    __shared__ float rmax[QT], rsum[QT], fac[QT];

    const float scale = 0.17677669529663687f;  // 32^-0.5
    const float* tab = table + (size_t)h * n_off;

    for (int b = 0; b < BATCH; ++b) {
        float qreg[KD];
        const float* qrow = qkv + (size_t)(b * LTOK + n0 + r) * (3 * DIMC) + h * (3 * KD);
        #pragma unroll
        for (int k = 0; k < KD; ++k) qreg[k] = qrow[k] * scale;
        float oacc0 = 0.f, oacc1 = 0.f;
        if (tid < QT) { rmax[tid] = -1e30f; rsum[tid] = 0.f; }
        __syncthreads();

        for (int mt = 0; mt < LTOK / MT; ++mt) {
            int m0 = mt * MT;
            #pragma unroll
            for (int i = 0; i < (MT * KD) / 256; ++i) {
                int e = tid + i * 256;
                int mr = e >> 5, kc = e & 31;
                const float* kvp = qkv + (size_t)(b * LTOK + m0 + mr) * (3 * DIMC) + h * (3 * KD);
                k_t[mr][kc] = kvp[KD + kc];
                v_t[mr][kc] = kvp[2 * KD + kc];
            }
            __syncthreads();

            float sv[4];
            {
                const int4 iv = *(const int4*)&bidx[(size_t)(n0 + r) * LTOK + m0 + c4];
                sv[0] = tab[iv.x]; sv[1] = tab[iv.y]; sv[2] = tab[iv.z]; sv[3] = tab[iv.w];
            }
            #pragma unroll
            for (int k = 0; k < KD; ++k) {
                float q = qreg[k];
                sv[0] += q * k_t[c4 + 0][k];
                sv[1] += q * k_t[c4 + 1][k];
                sv[2] += q * k_t[c4 + 2][k];
                sv[3] += q * k_t[c4 + 3][k];
            }
            float tm = fmaxf(fmaxf(sv[0], sv[1]), fmaxf(sv[2], sv[3]));
            red[r][tid & 15] = tm;
            __syncthreads();
            if (tid < QT) {
                float m = red[tid][0];
                #pragma unroll
                for (int i = 1; i < 16; ++i) m = fmaxf(m, red[tid][i]);
                float nm = fmaxf(rmax[tid], m);
                fac[tid] = __expf(rmax[tid] - nm);
                rmax[tid] = nm;
            }
            __syncthreads();
            float nm = rmax[r];
            float psum = 0.f;
            #pragma unroll
            for (int j = 0; j < 4; ++j) {
                sv[j] = __expf(sv[j] - nm);
                psum += sv[j];
                s_t[r][c4 + j] = sv[j];
            }
            red[r][tid & 15] = psum;
            __syncthreads();
            if (tid < QT) {
                float s = 0.f;
                #pragma unroll
                for (int i = 0; i < 16; ++i) s += red[tid][i];
                rsum[tid] = rsum[tid] * fac[tid] + s;
            }
            float f = fac[r];
            oacc0 *= f; oacc1 *= f;
            #pragma unroll
            for (int m = 0; m < MT; ++m) {
                float p = s_t[r][m];
                oacc0 += p * v_t[m][d0];
                oacc1 += p * v_t[m][d0 + 1];
            }
            __syncthreads();
        }
        float invl = 1.0f / rsum[r];
        float* orow = o + (size_t)(b * LTOK + n0 + r) * DIMC + h * KD;
        orow[d0]     = oacc0 * invl;
        orow[d0 + 1] = oacc1 * invl;
        __syncthreads();
    }
}

// ---------------- Depthwise 3x3 conv (per segment) + BN affine -------------
__global__ void conv_bn_kernel(const float* __restrict__ xm,
                               const float* __restrict__ w,
                               const float* __restrict__ scale,
                               const float* __restrict__ bias,
                               float* __restrict__ out) {
    int p = blockIdx.x;          // 0..NROWS-1
    int b = p / LTOK;
    int t = p - b * LTOK;
    int c = threadIdx.x;
    int H, W, base, y, x;
    if (t < 1024) { H = 32; W = 32; base = 0;    y = t >> 5;            x = t & 31; }
    else          { H = 16; W = 16; base = 1024; int tt = t - 1024; y = tt >> 4; x = tt & 15; }
    float acc = 0.f;
    #pragma unroll
    for (int ky = 0; ky < 3; ++ky) {
        int yy = y + ky - 1;
        if (yy < 0 || yy >= H) continue;
        #pragma unroll
        for (int kx = 0; kx < 3; ++kx) {
            int xx = x + kx - 1;
            if (xx < 0 || xx >= W) continue;
            acc += w[(ky * 3 + kx) * DIMC + c] *
                   xm[(size_t)(b * LTOK + base + yy * W + xx) * DIMC + c];
        }
    }
    out[(size_t)(b * LTOK + t) * DIMC + c] = acc * scale[c] + bias[c];
}

// ---------------------------------------------------------------------------
extern "C" void kernel_launch(void* const* d_in, const int* in_sizes, int n_in,
                              void* d_out, int out_size, void* d_ws, size_t ws_size,
                              hipStream_t stream) {
    const float* xz       = (const float*)d_in[0];
    const int*   bidx     = (const int*)  d_in[1];
    const float* ln1_g    = (const float*)d_in[2];
    const float* ln1_b    = (const float*)d_in[3];
    const float* wqkv     = (const float*)d_in[4];
    const float* bqkv     = (const float*)d_in[5];
    const float* wproj    = (const float*)d_in[6];
    const float* bproj    = (const float*)d_in[7];
    const float* btab     = (const float*)d_in[8];
    const float* conv_w   = (const float*)d_in[9];
    const float* bn_scale = (const float*)d_in[10];
    const float* bn_bias  = (const float*)d_in[11];
    const float* ln2_g    = (const float*)d_in[12];
    const float* ln2_b    = (const float*)d_in[13];
    const float* w1       = (const float*)d_in[14];
    const float* b1       = (const float*)d_in[15];
    const float* w2       = (const float*)d_in[16];
    const float* b2       = (const float*)d_in[17];
    int n_off = in_sizes[8] / HEADS;
    float* out = (float*)d_out;

    // workspace layout (floats)
    float* ws   = (float*)d_ws;
    float* hbuf = ws;                        // 10240*192  (h, later mln)
    float* big  = hbuf + (size_t)NROWS * DIMC;   // 10240*768 (qkv first, hid later)
    float* ob   = big  + (size_t)NROWS * HID;    // 10240*192
    float* xm   = ob   + (size_t)NROWS * DIMC;   // 10240*192
    float* xm2  = xm   + (size_t)NROWS * DIMC;   // 10240*192

    // 1) LN1
    ln_kernel<<<NROWS / 4, 256, 0, stream>>>(xz, ln1_g, ln1_b, hbuf);
    // 2) QKV GEMM (N=576)
    gemm_kernel<0,0><<<dim3(576 / 64, NROWS / 64), 256, 0, stream>>>(
        hbuf, wqkv, bqkv, nullptr, big, NROWS, 3 * DIMC, DIMC);
    // 3) attention
    attn_kernel<<<dim3(LTOK / QT, HEADS), 256, 0, stream>>>(big, bidx, btab, n_off, ob);
    // 4) proj + residual (xz)
    gemm_kernel<0,1><<<dim3(DIMC / 64, NROWS / 64), 256, 0, stream>>>(
        ob, wproj, bproj, xz, xm, NROWS, DIMC, DIMC);
    // 5) depthwise conv + BN
    conv_bn_kernel<<<NROWS, DIMC, 0, stream>>>(xm, conv_w, bn_scale, bn_bias, xm2);
    // 6) LN2 (reuse hbuf)
    ln_kernel<<<NROWS / 4, 256, 0, stream>>>(xm2, ln2_g, ln2_b, hbuf);
    // 7) MLP fc1 + exact GELU (reuse big as hidden)
    gemm_kernel<1,0><<<dim3(HID / 64, NROWS / 64), 256, 0, stream>>>(
        hbuf, w1, b1, nullptr, big, NROWS, HID, DIMC);
    // 8) MLP fc2 + residual (xm2) -> out
    gemm_kernel<0,1><<<dim3(DIMC / 64, NROWS / 64), 256, 0, stream>>>(
        big, w2, b2, xm2, out, NROWS, DIMC, HID);
}

// Round 2
// 315.058 us; speedup vs baseline: 4.2672x; 4.2672x over previous
//
#include <hip/hip_runtime.h>
#include <hip/hip_bf16.h>

#define BATCH 8
#define LTOK 1280
#define DIMC 192
#define HEADS 6
#define KD 32
#define HID 768
#define NROWS (BATCH*LTOK)   // 10240

typedef short s16x8 __attribute__((ext_vector_type(8)));
typedef float f32x4 __attribute__((ext_vector_type(4)));

__device__ __forceinline__ unsigned short f2bf(float x) {
    unsigned u = __float_as_uint(x);
    u = (u + 0x7FFFu + ((u >> 16) & 1u)) >> 16;
    return (unsigned short)u;
}

// ---------------- LayerNorm: 4 rows/block, 64 lanes per row ----------------
__global__ __launch_bounds__(256) void ln_kernel(const float* __restrict__ x,
                                                 const float* __restrict__ g,
                                                 const float* __restrict__ b,
                                                 float* __restrict__ y) {
    int row = blockIdx.x * 4 + (threadIdx.x >> 6);
    int lane = threadIdx.x & 63;
    const float* xr = x + (size_t)row * DIMC;
    float v0 = xr[lane], v1 = xr[lane + 64], v2 = xr[lane + 128];
    float s = v0 + v1 + v2;
    float ss = v0 * v0 + v1 * v1 + v2 * v2;
    #pragma unroll
    for (int off = 32; off; off >>= 1) {
        s  += __shfl_xor(s, off);
        ss += __shfl_xor(ss, off);
    }
    float mu  = s * (1.0f / DIMC);
    float var = ss * (1.0f / DIMC) - mu * mu;
    float inv = rsqrtf(var + 1e-5f);
    float* yr = y + (size_t)row * DIMC;
    yr[lane]       = (v0 - mu) * inv * g[lane]       + b[lane];
    yr[lane + 64]  = (v1 - mu) * inv * g[lane + 64]  + b[lane + 64];
    yr[lane + 128] = (v2 - mu) * inv * g[lane + 128] + b[lane + 128];
}

// ---------------- Generic fp32 GEMM: C = act(A@W + bias) (+R) --------------
// OBF: 0 = f32 out, 1 = bf16 out
template<int ACT, int RES, int OBF>
__global__ __launch_bounds__(256) void gemm_kernel(const float* __restrict__ A,
                                                   const float* __restrict__ W,
                                                   const float* __restrict__ bias,
                                                   const float* __restrict__ R,
                                                   void* __restrict__ Cp,
                                                   int M, int N, int K) {
    __shared__ float As[64][17];
    __shared__ float Ws[16][64];
    int tid = threadIdx.x;
    int tx = tid & 15, ty = tid >> 4;
    int m0 = blockIdx.y * 64, n0 = blockIdx.x * 64;
    float acc[4][4] = {};
    for (int k0 = 0; k0 < K; k0 += 16) {
        #pragma unroll
        for (int i = 0; i < 4; ++i) {
            int e = tid + i * 256;
            int ar = e >> 4, ac = e & 15;
            As[ar][ac] = A[(size_t)(m0 + ar) * K + k0 + ac];
        }
        #pragma unroll
        for (int i = 0; i < 4; ++i) {
            int e = tid + i * 256;
            int kr = e >> 6, nc = e & 63;
            Ws[kr][nc] = W[(size_t)(k0 + kr) * N + n0 + nc];
        }
        __syncthreads();
        #pragma unroll
        for (int kk = 0; kk < 16; ++kk) {
            float a0 = As[ty * 4 + 0][kk];
            float a1 = As[ty * 4 + 1][kk];
            float a2 = As[ty * 4 + 2][kk];
            float a3 = As[ty * 4 + 3][kk];
            float4 wv = *(const float4*)&Ws[kk][tx * 4];
            float w[4] = {wv.x, wv.y, wv.z, wv.w};
            float a[4] = {a0, a1, a2, a3};
            #pragma unroll
            for (int i = 0; i < 4; ++i)
                #pragma unroll
                for (int j = 0; j < 4; ++j)
                    acc[i][j] += a[i] * w[j];
        }
        __syncthreads();
    }
    #pragma unroll
    for (int i = 0; i < 4; ++i) {
        int row = m0 + ty * 4 + i;
        #pragma unroll
        for (int j = 0; j < 4; ++j) {
            int col = n0 + tx * 4 + j;
            float v = acc[i][j] + bias[col];
            if (ACT == 1) v = 0.5f * v * (1.0f + erff(v * 0.70710678118654752f));
            if (RES) v += R[(size_t)row * N + col];
            if (OBF) ((unsigned short*)Cp)[(size_t)row * N + col] = f2bf(v);
            else     ((float*)Cp)[(size_t)row * N + col] = v;
        }
    }
}

// ---------------- V transpose: qkv bf16 -> Vt[b][h][d][token] --------------
__global__ __launch_bounds__(256) void vtrans_kernel(const unsigned short* __restrict__ qkvb,
                                                     unsigned short* __restrict__ vt) {
    int tok = blockIdx.x * 256 + threadIdx.x;   // 0..10239
    int b = tok / LTOK, t = tok - b * LTOK;
    #pragma unroll
    for (int h = 0; h < HEADS; ++h) {
        union { uint4 q[4]; unsigned short u[32]; } v;
        const uint4* src = (const uint4*)(qkvb + (size_t)tok * 576 + h * 96 + 64);
        v.q[0] = src[0]; v.q[1] = src[1]; v.q[2] = src[2]; v.q[3] = src[3];
        unsigned short* dst = vt + ((size_t)(b * HEADS + h) * KD) * LTOK + t;
        #pragma unroll
        for (int d = 0; d < 32; ++d) dst[(size_t)d * LTOK] = v.u[d];
    }
}

// ---------------- MFMA flash attention: one wave per (b,h,16-row q-tile) ---
// S^T = K.Q^T via mfma_16x16x32_bf16 with permuted K rows so that the C
// layout of S^T equals the A-fragment layout of the PV mfma (no shuffles).
__global__ __launch_bounds__(256) void attn_mfma(const unsigned short* __restrict__ qkvb,
                                                 const unsigned short* __restrict__ vt,
                                                 const int* __restrict__ bidx,
                                                 const float* __restrict__ table,
                                                 int n_off,
                                                 float* __restrict__ ob) {
    int L = threadIdx.x & 63;
    int w = threadIdx.x >> 6;
    int bx = blockIdx.x;
    int qt = (bx % 20) * 4 + w;          // 0..79
    int h  = (bx / 20) % HEADS;
    int b  = bx / (20 * HEADS);
    int r  = L & 15;
    int g  = L >> 4;                     // 0..3
    const float* tab = table + (size_t)h * n_off;

    size_t qrow = (size_t)(b * LTOK + qt * 16 + r);
    s16x8 qf = *(const s16x8*)(qkvb + qrow * 576 + h * 96 + g * 8);

    int kperm = ((r >> 2) << 3) | (r & 3);   // rows 0..15 -> keys {0..3,8..11,16..19,24..27}
    f32x4 acc0 = {0.f, 0.f, 0.f, 0.f}, acc1 = {0.f, 0.f, 0.f, 0.f};
    float m_run = -1e30f, l_run = 0.f;

    const int* brow = bidx + (size_t)(qt * 16 + r) * LTOK;
    const unsigned short* vbase0 = vt + ((size_t)(b * HEADS + h) * KD + r) * LTOK;
    const unsigned short* vbase1 = vbase0 + (size_t)16 * LTOK;
    const unsigned short* kbase = qkvb + (size_t)(b * LTOK) * 576 + h * 96 + 32 + g * 8;
    const float sc = 0.17677669529663687f;   // 32^-0.5

    for (int T = 0; T < LTOK / 32; ++T) {
        int k0 = T * 32 + kperm;
        s16x8 kf0 = *(const s16x8*)(kbase + (size_t)k0 * 576);
        s16x8 kf1 = *(const s16x8*)(kbase + (size_t)(k0 + 4) * 576);
        f32x4 z = {0.f, 0.f, 0.f, 0.f};
        f32x4 s0 = __builtin_amdgcn_mfma_f32_16x16x32_bf16(kf0, qf, z, 0, 0, 0);
        f32x4 s1 = __builtin_amdgcn_mfma_f32_16x16x32_bf16(kf1, qf, z, 0, 0, 0);
        int4 iv0 = *(const int4*)(brow + T * 32 + g * 8);
        int4 iv1 = *(const int4*)(brow + T * 32 + g * 8 + 4);
        float sf[8];
        sf[0] = s0[0] * sc + tab[iv0.x];
        sf[1] = s0[1] * sc + tab[iv0.y];
        sf[2] = s0[2] * sc + tab[iv0.z];
        sf[3] = s0[3] * sc + tab[iv0.w];
        sf[4] = s1[0] * sc + tab[iv1.x];
        sf[5] = s1[1] * sc + tab[iv1.y];
        sf[6] = s1[2] * sc + tab[iv1.z];
        sf[7] = s1[3] * sc + tab[iv1.w];
        float tm = sf[0];
        #pragma unroll
        for (int j = 1; j < 8; ++j) tm = fmaxf(tm, sf[j]);
        tm = fmaxf(tm, __shfl_xor(tm, 16));
        tm = fmaxf(tm, __shfl_xor(tm, 32));
        float mn = fmaxf(m_run, tm);
        float f = __expf(m_run - mn);
        float p[8], ls = 0.f;
        #pragma unroll
        for (int j = 0; j < 8; ++j) { p[j] = __expf(sf[j] - mn); ls += p[j]; }
        ls += __shfl_xor(ls, 16);
        ls += __shfl_xor(ls, 32);
        l_run = l_run * f + ls;
        m_run = mn;
        float fa0 = __shfl(f, 4 * g + 0);
        float fa1 = __shfl(f, 4 * g + 1);
        float fa2 = __shfl(f, 4 * g + 2);
        float fa3 = __shfl(f, 4 * g + 3);
        acc0[0] *= fa0; acc0[1] *= fa1; acc0[2] *= fa2; acc0[3] *= fa3;
        acc1[0] *= fa0; acc1[1] *= fa1; acc1[2] *= fa2; acc1[3] *= fa3;
        s16x8 pb;
        #pragma unroll
        for (int j = 0; j < 8; ++j) pb[j] = (short)f2bf(p[j]);
        s16x8 v0 = *(const s16x8*)(vbase0 + T * 32 + g * 8);
        s16x8 v1 = *(const s16x8*)(vbase1 + T * 32 + g * 8);
        acc0 = __builtin_amdgcn_mfma_f32_16x16x32_bf16(pb, v0, acc0, 0, 0, 0);
        acc1 = __builtin_amdgcn_mfma_f32_16x16x32_bf16(pb, v1, acc1, 0, 0, 0);
    }
    #pragma unroll
    for (int i = 0; i < 4; ++i) {
        float linv = 1.0f / __shfl(l_run, 4 * g + i);
        size_t orow = (size_t)(b * LTOK + qt * 16 + 4 * g + i) * DIMC + h * KD + r;
        ob[orow]      = acc0[i] * linv;
        ob[orow + 16] = acc1[i] * linv;
    }
}

// ---------------- Depthwise 3x3 conv (per segment) + BN affine -------------
__global__ void conv_bn_kernel(const float* __restrict__ xm,
                               const float* __restrict__ w,
                               const float* __restrict__ scale,
                               const float* __restrict__ bias,
                               float* __restrict__ out) {
    int p = blockIdx.x;          // 0..NROWS-1
    int b = p / LTOK;
    int t = p - b * LTOK;
    int c = threadIdx.x;
    int H, W, base, y, x;
    if (t < 1024) { H = 32; W = 32; base = 0;    y = t >> 5;            x = t & 31; }
    else          { H = 16; W = 16; base = 1024; int tt = t - 1024; y = tt >> 4; x = tt & 15; }
    float acc = 0.f;
    #pragma unroll
    for (int ky = 0; ky < 3; ++ky) {
        int yy = y + ky - 1;
        if (yy < 0 || yy >= H) continue;
        #pragma unroll
        for (int kx = 0; kx < 3; ++kx) {
            int xx = x + kx - 1;
            if (xx < 0 || xx >= W) continue;
            acc += w[(ky * 3 + kx) * DIMC + c] *
                   xm[(size_t)(b * LTOK + base + yy * W + xx) * DIMC + c];
        }
    }
    out[(size_t)(b * LTOK + t) * DIMC + c] = acc * scale[c] + bias[c];
}

// ---------------------------------------------------------------------------
extern "C" void kernel_launch(void* const* d_in, const int* in_sizes, int n_in,
                              void* d_out, int out_size, void* d_ws, size_t ws_size,
                              hipStream_t stream) {
    const float* xz       = (const float*)d_in[0];
    const int*   bidx     = (const int*)  d_in[1];
    const float* ln1_g    = (const float*)d_in[2];
    const float* ln1_b    = (const float*)d_in[3];
    const float* wqkv     = (const float*)d_in[4];
    const float* bqkv     = (const float*)d_in[5];
    const float* wproj    = (const float*)d_in[6];
    const float* bproj    = (const float*)d_in[7];
    const float* btab     = (const float*)d_in[8];
    const float* conv_w   = (const float*)d_in[9];
    const float* bn_scale = (const float*)d_in[10];
    const float* bn_bias  = (const float*)d_in[11];
    const float* ln2_g    = (const float*)d_in[12];
    const float* ln2_b    = (const float*)d_in[13];
    const float* w1       = (const float*)d_in[14];
    const float* b1       = (const float*)d_in[15];
    const float* w2       = (const float*)d_in[16];
    const float* b2       = (const float*)d_in[17];
    int n_off = in_sizes[8] / HEADS;
    float* out = (float*)d_out;

    // ---- workspace layout (bytes) ----
    // [0, 7.86M)   xm2 (f32, live steps 5..8)
    // [7.86M,15.7M) hbuf (f32, live 1..2 and 6..7)
    // [15.7M, 47.2M) U: {qkvb bf16 11.80M | Vt bf16 3.93M | ob f32 7.86M | xm f32 7.86M}
    //                 later reused wholesale as hid (f32, 31.46M) in steps 7..8
    char* wsb = (char*)d_ws;
    float* xm2  = (float*)(wsb);
    float* hbuf = (float*)(wsb + (size_t)NROWS * DIMC * 4);
    char*  U    = wsb + (size_t)2 * NROWS * DIMC * 4;
    unsigned short* qkvb = (unsigned short*)U;                                   // 11,796,480 B
    unsigned short* vtb  = (unsigned short*)(U + (size_t)NROWS * 576 * 2);       //  3,932,160 B
    float* ob   = (float*)(U + (size_t)NROWS * 576 * 2 + (size_t)BATCH * HEADS * KD * LTOK * 2);
    float* xm   = ob + (size_t)NROWS * DIMC;
    float* hid  = (float*)U;                                                     // 31,457,280 B

    // 1) LN1
    ln_kernel<<<NROWS / 4, 256, 0, stream>>>(xz, ln1_g, ln1_b, hbuf);
    // 2) QKV GEMM (N=576) -> bf16
    gemm_kernel<0,0,1><<<dim3(576 / 64, NROWS / 64), 256, 0, stream>>>(
        hbuf, wqkv, bqkv, nullptr, qkvb, NROWS, 3 * DIMC, DIMC);
    // 2.5) V transpose
    vtrans_kernel<<<NROWS / 256, 256, 0, stream>>>(qkvb, vtb);
    // 3) attention (MFMA flash)
    attn_mfma<<<BATCH * HEADS * (LTOK / 64), 256, 0, stream>>>(qkvb, vtb, bidx, btab, n_off, ob);
    // 4) proj + residual (xz)
    gemm_kernel<0,1,0><<<dim3(DIMC / 64, NROWS / 64), 256, 0, stream>>>(
        ob, wproj, bproj, xz, xm, NROWS, DIMC, DIMC);
    // 5) depthwise conv + BN
    conv_bn_kernel<<<NROWS, DIMC, 0, stream>>>(xm, conv_w, bn_scale, bn_bias, xm2);
    // 6) LN2 (reuse hbuf)
    ln_kernel<<<NROWS / 4, 256, 0, stream>>>(xm2, ln2_g, ln2_b, hbuf);
    // 7) MLP fc1 + exact GELU (hid overlays qkvb/vtb/ob/xm — all dead now)
    gemm_kernel<1,0,0><<<dim3(HID / 64, NROWS / 64), 256, 0, stream>>>(
        hbuf, w1, b1, nullptr, hid, NROWS, HID, DIMC);
    // 8) MLP fc2 + residual (xm2) -> out
    gemm_kernel<0,1,0><<<dim3(DIMC / 64, NROWS / 64), 256, 0, stream>>>(
        hid, w2, b2, xm2, out, NROWS, DIMC, HID);
}

// Round 3
// 187.458 us; speedup vs baseline: 7.1718x; 1.6807x over previous
//
#include <hip/hip_runtime.h>
#include <hip/hip_bf16.h>

#define BATCH 8
#define LTOK 1280
#define DIMC 192
#define HEADS 6
#define KD 32
#define HID 768
#define NROWS (BATCH*LTOK)   // 10240

typedef short s16x8 __attribute__((ext_vector_type(8)));
typedef float f32x4 __attribute__((ext_vector_type(4)));
typedef unsigned short u16;

// q pre-scale: 32^-0.5 * log2(e)  (softmax runs in exp2 domain)
#define QS (0.17677669529663687f * 1.4426950408889634f)
#define L2E 1.4426950408889634f

__device__ __forceinline__ u16 f2bf(float x) {
    unsigned u = __float_as_uint(x);
    u = (u + 0x7FFFu + ((u >> 16) & 1u)) >> 16;
    return (u16)u;
}
__device__ __forceinline__ float bflo(unsigned u) { return __uint_as_float(u << 16); }
__device__ __forceinline__ float bfhi(unsigned u) { return __uint_as_float(u & 0xffff0000u); }

// ---------------- LayerNorm -> bf16: 4 rows/block, 64 lanes per row --------
__global__ __launch_bounds__(256) void ln_kernel(const float* __restrict__ x,
                                                 const float* __restrict__ g,
                                                 const float* __restrict__ b,
                                                 u16* __restrict__ y) {
    int row = blockIdx.x * 4 + (threadIdx.x >> 6);
    int lane = threadIdx.x & 63;
    const float* xr = x + (size_t)row * DIMC;
    float v0 = xr[lane], v1 = xr[lane + 64], v2 = xr[lane + 128];
    float s = v0 + v1 + v2;
    float ss = v0 * v0 + v1 * v1 + v2 * v2;
    #pragma unroll
    for (int off = 32; off; off >>= 1) {
        s  += __shfl_xor(s, off);
        ss += __shfl_xor(ss, off);
    }
    float mu  = s * (1.0f / DIMC);
    float var = ss * (1.0f / DIMC) - mu * mu;
    float inv = rsqrtf(var + 1e-5f);
    u16* yr = y + (size_t)row * DIMC;
    yr[lane]       = f2bf((v0 - mu) * inv * g[lane]       + b[lane]);
    yr[lane + 64]  = f2bf((v1 - mu) * inv * g[lane + 64]  + b[lane + 64]);
    yr[lane + 128] = f2bf((v2 - mu) * inv * g[lane + 128] + b[lane + 128]);
}

// ---------------- Weight transpose+convert: W[K][N] f32 -> Wt[N][K] bf16 ---
__global__ __launch_bounds__(256) void wtrans_kernel(const float* w0, const float* w1,
                                                     const float* w2, const float* w3,
                                                     u16* o0, u16* o1, u16* o2, u16* o3) {
    __shared__ float s[16][17];
    int f = blockIdx.x;
    const float* in; u16* out; int K, N, tn, tk;
    if (f < 432)       { in = w0; out = o0; K = 192; N = 576; int r = f;        tn = r % 36; tk = r / 36; }
    else if (f < 576)  { in = w1; out = o1; K = 192; N = 192; int r = f - 432;  tn = r % 12; tk = r / 12; }
    else if (f < 1152) { in = w2; out = o2; K = 192; N = 768; int r = f - 576;  tn = r % 48; tk = r / 48; }
    else               { in = w3; out = o3; K = 768; N = 192; int r = f - 1152; tn = r % 12; tk = r / 12; }
    int tx = threadIdx.x & 15, ty = threadIdx.x >> 4;
    s[ty][tx] = in[(size_t)(tk * 16 + ty) * N + tn * 16 + tx];
    __syncthreads();
    out[(size_t)(tn * 16 + ty) * K + tk * 16 + tx] = f2bf(s[tx][ty]);
}

// ---------------- Bias matrix precompute: bm[h][n][m] = bf16(tab*log2e) ----
__global__ __launch_bounds__(256) void biasmat_kernel(const int* __restrict__ bidx,
                                                      const float* __restrict__ btab,
                                                      int n_off, u16* __restrict__ bm) {
    int h = blockIdx.y;
    size_t flat = (size_t)blockIdx.x * 1024 + (size_t)threadIdx.x * 4;
    int4 iv = *(const int4*)(bidx + flat);
    const float* tab = btab + (size_t)h * n_off;
    ushort4 o;
    o.x = f2bf(tab[iv.x] * L2E);
    o.y = f2bf(tab[iv.y] * L2E);
    o.z = f2bf(tab[iv.z] * L2E);
    o.w = f2bf(tab[iv.w] * L2E);
    *(ushort4*)(bm + (size_t)h * (LTOK * LTOK) + flat) = o;
}

// ---------------- MFMA GEMM: C = act(A@W + bias) (+R)  --------------------
// A bf16 [M][K] row-major, Wt bf16 [N][K] (W transposed). 256 thr = 4 waves,
// block tile 64(M)x64(N), wave tile 16x64. K%32==0.
// QKV=1: special epilogue scattering q (scaled) / K / V into attn layouts.
template<int ACT, int RES, int OBF, int QKV>
__global__ __launch_bounds__(256) void gemm_mfma(const u16* __restrict__ A,
                                                 const u16* __restrict__ Wt,
                                                 const float* __restrict__ bias,
                                                 const float* __restrict__ R,
                                                 void* __restrict__ Cp,
                                                 u16* __restrict__ qb,
                                                 u16* __restrict__ kp,
                                                 u16* __restrict__ vp,
                                                 int M, int N, int K) {
    int tid = threadIdx.x;
    int L = tid & 63, w = tid >> 6;
    int r = L & 15, g = L >> 4;
    int m0 = blockIdx.y * 64 + w * 16;
    int n0 = blockIdx.x * 64;

    f32x4 acc[4] = {};
    const u16* Ab = A + (size_t)(m0 + r) * K + g * 8;
    const u16* Wb = Wt + (size_t)(n0 + r) * K + g * 8;
    for (int k0 = 0; k0 < K; k0 += 32) {
        s16x8 af = *(const s16x8*)(Ab + k0);
        #pragma unroll
        for (int nn = 0; nn < 4; ++nn) {
            s16x8 bf = *(const s16x8*)(Wb + (size_t)nn * 16 * K + k0);
            acc[nn] = __builtin_amdgcn_mfma_f32_16x16x32_bf16(af, bf, acc[nn], 0, 0, 0);
        }
    }

    #pragma unroll
    for (int nn = 0; nn < 4; ++nn) {
        int cb = n0 + nn * 16;
        #pragma unroll
        for (int i = 0; i < 4; ++i) {
            int row = m0 + g * 4 + i;
            float v = acc[nn][i] + bias[cb + r];
            if (QKV) {
                int h  = cb / 96, c0 = cb % 96;
                int reg = c0 >> 5;               // 0=q, 1=k, 2=v
                if (reg == 0) {
                    v *= QS;
                    qb[(size_t)row * DIMC + h * 32 + (c0 & 31) + r] = f2bf(v);
                } else {
                    int b_ = row / LTOK, t = row - b_ * LTOK;
                    int T = t >> 5, it = t & 31;
                    int d = (c0 & 31) + r;
                    if (reg == 1) {
                        int which = (it >> 2) & 1;
                        int ik = ((it >> 3) << 2) | (it & 3);
                        int Lk = ((d >> 3) << 4) + ik;
                        kp[((size_t)(b_ * HEADS + h) * 40 + T) * 1024 + which * 512 + Lk * 8 + (d & 7)] = f2bf(v);
                    } else {
                        int Lv = ((it >> 3) << 4) + (d & 15);
                        vp[((size_t)(b_ * HEADS + h) * 40 + T) * 1024 + (d >> 4) * 512 + Lv * 8 + (it & 7)] = f2bf(v);
                    }
                }
            } else {
                if (ACT == 1) v = 0.5f * v * (1.0f + erff(v * 0.70710678118654752f));
                if (RES) v += R[(size_t)row * N + cb + r];
                if (OBF) ((u16*)Cp)[(size_t)row * N + cb + r] = f2bf(v);
                else     ((float*)Cp)[(size_t)row * N + cb + r] = v;
            }
        }
    }
}

// ---------------- MFMA flash attention, fragment-packed operands -----------
__global__ __launch_bounds__(256) void attn_mfma(const u16* __restrict__ qb,
                                                 const u16* __restrict__ kp,
                                                 const u16* __restrict__ vp,
                                                 const u16* __restrict__ bm,
                                                 u16* __restrict__ ob) {
    int L = threadIdx.x & 63;
    int w = threadIdx.x >> 6;
    int bx = blockIdx.x;
    int qt = (bx % 20) * 4 + w;
    int h  = (bx / 20) % HEADS;
    int b  = bx / (20 * HEADS);
    int r  = L & 15;
    int g  = L >> 4;

    s16x8 qf = *(const s16x8*)(qb + (size_t)(b * LTOK + qt * 16 + r) * DIMC + h * 32 + g * 8);
    const u16* kpt = kp + (size_t)(b * HEADS + h) * 40 * 1024 + L * 8;
    const u16* vpt = vp + (size_t)(b * HEADS + h) * 40 * 1024 + L * 8;
    const u16* bmr = bm + ((size_t)h * LTOK + qt * 16 + r) * LTOK + g * 8;

    f32x4 acc0 = {0.f, 0.f, 0.f, 0.f}, acc1 = {0.f, 0.f, 0.f, 0.f};
    float m_run = -1e30f, l_run = 0.f;

    for (int T = 0; T < LTOK / 32; ++T) {
        s16x8 kf0 = *(const s16x8*)(kpt + T * 1024);
        s16x8 kf1 = *(const s16x8*)(kpt + T * 1024 + 512);
        f32x4 z = {0.f, 0.f, 0.f, 0.f};
        f32x4 s0 = __builtin_amdgcn_mfma_f32_16x16x32_bf16(kf0, qf, z, 0, 0, 0);
        f32x4 s1 = __builtin_amdgcn_mfma_f32_16x16x32_bf16(kf1, qf, z, 0, 0, 0);
        int4 bv = *(const int4*)(bmr + T * 32);
        float sf[8];
        sf[0] = s0[0] + bflo(bv.x); sf[1] = s0[1] + bfhi(bv.x);
        sf[2] = s0[2] + bflo(bv.y); sf[3] = s0[3] + bfhi(bv.y);
        sf[4] = s1[0] + bflo(bv.z); sf[5] = s1[1] + bfhi(bv.z);
        sf[6] = s1[2] + bflo(bv.w); sf[7] = s1[3] + bfhi(bv.w);
        float tm = fmaxf(fmaxf(fmaxf(sf[0], sf[1]), fmaxf(sf[2], sf[3])),
                         fmaxf(fmaxf(sf[4], sf[5]), fmaxf(sf[6], sf[7])));
        tm = fmaxf(tm, __shfl_xor(tm, 16));
        tm = fmaxf(tm, __shfl_xor(tm, 32));
        // defer-max: only rescale when a row grew by > 8 (exp2 domain)
        if (!__all(tm <= m_run + 8.0f)) {
            float mn = fmaxf(m_run, tm);
            float f = exp2f(m_run - mn);
            m_run = mn;
            l_run *= f;
            float fa0 = __shfl(f, 4 * g + 0);
            float fa1 = __shfl(f, 4 * g + 1);
            float fa2 = __shfl(f, 4 * g + 2);
            float fa3 = __shfl(f, 4 * g + 3);
            acc0[0] *= fa0; acc0[1] *= fa1; acc0[2] *= fa2; acc0[3] *= fa3;
            acc1[0] *= fa0; acc1[1] *= fa1; acc1[2] *= fa2; acc1[3] *= fa3;
        }
        float p[8], ls = 0.f;
        #pragma unroll
        for (int j = 0; j < 8; ++j) { p[j] = exp2f(sf[j] - m_run); ls += p[j]; }
        ls += __shfl_xor(ls, 16);
        ls += __shfl_xor(ls, 32);
        l_run += ls;
        union { unsigned u[4]; s16x8 v; } pbu;
        #pragma unroll
        for (int j = 0; j < 4; ++j)
            asm("v_cvt_pk_bf16_f32 %0, %1, %2" : "=v"(pbu.u[j]) : "v"(p[2 * j]), "v"(p[2 * j + 1]));
        s16x8 v0 = *(const s16x8*)(vpt + T * 1024);
        s16x8 v1 = *(const s16x8*)(vpt + T * 1024 + 512);
        acc0 = __builtin_amdgcn_mfma_f32_16x16x32_bf16(pbu.v, v0, acc0, 0, 0, 0);
        acc1 = __builtin_amdgcn_mfma_f32_16x16x32_bf16(pbu.v, v1, acc1, 0, 0, 0);
    }
    #pragma unroll
    for (int i = 0; i < 4; ++i) {
        float linv = 1.0f / __shfl(l_run, 4 * g + i);
        size_t orow = (size_t)(b * LTOK + qt * 16 + 4 * g + i) * DIMC + h * 32 + r;
        ob[orow]      = f2bf(acc0[i] * linv);
        ob[orow + 16] = f2bf(acc1[i] * linv);
    }
}

// ---------------- Depthwise 3x3 conv (per segment) + BN affine -------------
__global__ void conv_bn_kernel(const float* __restrict__ xm,
                               const float* __restrict__ w,
                               const float* __restrict__ scale,
                               const float* __restrict__ bias,
                               float* __restrict__ out) {
    int p = blockIdx.x;
    int b = p / LTOK;
    int t = p - b * LTOK;
    int c = threadIdx.x;
    int H, W, base, y, x;
    if (t < 1024) { H = 32; W = 32; base = 0;    y = t >> 5;            x = t & 31; }
    else          { H = 16; W = 16; base = 1024; int tt = t - 1024; y = tt >> 4; x = tt & 15; }
    float acc = 0.f;
    #pragma unroll
    for (int ky = 0; ky < 3; ++ky) {
        int yy = y + ky - 1;
        if (yy < 0 || yy >= H) continue;
        #pragma unroll
        for (int kx = 0; kx < 3; ++kx) {
            int xx = x + kx - 1;
            if (xx < 0 || xx >= W) continue;
            acc += w[(ky * 3 + kx) * DIMC + c] *
                   xm[(size_t)(b * LTOK + base + yy * W + xx) * DIMC + c];
        }
    }
    out[(size_t)(b * LTOK + t) * DIMC + c] = acc * scale[c] + bias[c];
}

// ---------------------------------------------------------------------------
extern "C" void kernel_launch(void* const* d_in, const int* in_sizes, int n_in,
                              void* d_out, int out_size, void* d_ws, size_t ws_size,
                              hipStream_t stream) {
    const float* xz       = (const float*)d_in[0];
    const int*   bidx     = (const int*)  d_in[1];
    const float* ln1_g    = (const float*)d_in[2];
    const float* ln1_b    = (const float*)d_in[3];
    const float* wqkv     = (const float*)d_in[4];
    const float* bqkv     = (const float*)d_in[5];
    const float* wproj    = (const float*)d_in[6];
    const float* bproj    = (const float*)d_in[7];
    const float* btab     = (const float*)d_in[8];
    const float* conv_w   = (const float*)d_in[9];
    const float* bn_scale = (const float*)d_in[10];
    const float* bn_bias  = (const float*)d_in[11];
    const float* ln2_g    = (const float*)d_in[12];
    const float* ln2_b    = (const float*)d_in[13];
    const float* w1       = (const float*)d_in[14];
    const float* b1       = (const float*)d_in[15];
    const float* w2       = (const float*)d_in[16];
    const float* b2       = (const float*)d_in[17];
    int n_off = in_sizes[8] / HEADS;
    float* out = (float*)d_out;

    // ---- workspace layout (bytes), with liveness overlays; peak 40.2 MB ----
    char* wsb = (char*)d_ws;
    u16*  hbuf   = (u16*)(wsb + 0);                    // 3,932,160  (ln out; ob overlays)
    u16*  ob     = (u16*)(wsb + 0);                    //   attn out (hbuf dead window)
    u16*  wqkvT  = (u16*)(wsb + 3932160);              //   221,184
    u16*  wprojT = (u16*)(wsb + 4153344);              //    73,728
    u16*  w1T    = (u16*)(wsb + 4227072);              //   294,912
    u16*  w2T    = (u16*)(wsb + 4521984);              //   294,912 -> 4,816,896
    u16*  bm     = (u16*)(wsb + 4816896);              // 19,660,800 -> 24,477,696
    u16*  hid    = (u16*)(wsb + 4816896);              //   fc1 out (bm dead) 15,728,640
    u16*  kp     = (u16*)(wsb + 24477696);             // 3,932,160
    u16*  vp     = (u16*)(wsb + 28409856);             // 3,932,160 -> 32,342,016
    float* xm2   = (float*)(wsb + 24477696);           //   conv out (kp/vp dead) 7,864,320
    u16*  qb     = (u16*)(wsb + 32342016);             // 3,932,160
    float* xm    = (float*)(wsb + 32342016);           //   proj out (qb dead) 7,864,320 -> 40,206,336

    // 1) weight transpose/convert (f32 -> bf16, [N][K])
    wtrans_kernel<<<1728, 256, 0, stream>>>(wqkv, wproj, w1, w2, wqkvT, wprojT, w1T, w2T);
    // 2) bias matrix precompute (exp2 domain)
    biasmat_kernel<<<dim3(LTOK * LTOK / 1024, HEADS), 256, 0, stream>>>(bidx, btab, n_off, bm);
    // 3) LN1 -> bf16
    ln_kernel<<<NROWS / 4, 256, 0, stream>>>(xz, ln1_g, ln1_b, hbuf);
    // 4) QKV GEMM, scattering q/K/V into attention layouts
    gemm_mfma<0,0,0,1><<<dim3(576 / 64, NROWS / 64), 256, 0, stream>>>(
        hbuf, wqkvT, bqkv, nullptr, nullptr, qb, kp, vp, NROWS, 3 * DIMC, DIMC);
    // 5) attention
    attn_mfma<<<BATCH * HEADS * (LTOK / 64), 256, 0, stream>>>(qb, kp, vp, bm, ob);
    // 6) proj + residual(xz) -> xm f32
    gemm_mfma<0,1,0,0><<<dim3(DIMC / 64, NROWS / 64), 256, 0, stream>>>(
        ob, wprojT, bproj, xz, xm, nullptr, nullptr, nullptr, NROWS, DIMC, DIMC);
    // 7) depthwise conv + BN -> xm2
    conv_bn_kernel<<<NROWS, DIMC, 0, stream>>>(xm, conv_w, bn_scale, bn_bias, xm2);
    // 8) LN2 -> bf16
    ln_kernel<<<NROWS / 4, 256, 0, stream>>>(xm2, ln2_g, ln2_b, hbuf);
    // 9) MLP fc1 + exact GELU -> hid bf16
    gemm_mfma<1,0,1,0><<<dim3(HID / 64, NROWS / 64), 256, 0, stream>>>(
        hbuf, w1T, b1, nullptr, hid, nullptr, nullptr, nullptr, NROWS, HID, DIMC);
    // 10) MLP fc2 + residual(xm2) -> out f32
    gemm_mfma<0,1,0,0><<<dim3(DIMC / 64, NROWS / 64), 256, 0, stream>>>(
        hid, w2T, b2, xm2, out, nullptr, nullptr, nullptr, NROWS, DIMC, HID);
}

// Round 4
// 160.272 us; speedup vs baseline: 8.3883x; 1.1696x over previous
//
#include <hip/hip_runtime.h>
#include <hip/hip_bf16.h>

#define BATCH 8
#define LTOK 1280
#define DIMC 192
#define HEADS 6
#define KD 32
#define HID 768
#define NROWS (BATCH*LTOK)   // 10240

typedef short s16x8 __attribute__((ext_vector_type(8)));
typedef float f32x4 __attribute__((ext_vector_type(4)));
typedef unsigned short u16;

// q pre-scale: 32^-0.5 * log2(e)  (softmax runs in exp2 domain)
#define QS (0.17677669529663687f * 1.4426950408889634f)
#define L2E 1.4426950408889634f

__device__ __forceinline__ u16 f2bf(float x) {
    unsigned u = __float_as_uint(x);
    u = (u + 0x7FFFu + ((u >> 16) & 1u)) >> 16;
    return (u16)u;
}
__device__ __forceinline__ float bflo(unsigned u) { return __uint_as_float(u << 16); }
__device__ __forceinline__ float bfhi(unsigned u) { return __uint_as_float(u & 0xffff0000u); }
__device__ __forceinline__ float fexp2(float x) { float r; asm("v_exp_f32 %0, %1" : "=v"(r) : "v"(x)); return r; }
__device__ __forceinline__ float frcp(float x)  { float r; asm("v_rcp_f32 %0, %1" : "=v"(r) : "v"(x)); return r; }

// ---------------- LayerNorm -> bf16: 4 rows/block, 64 lanes per row --------
__global__ __launch_bounds__(256) void ln_kernel(const float* __restrict__ x,
                                                 const float* __restrict__ g,
                                                 const float* __restrict__ b,
                                                 u16* __restrict__ y) {
    int row = blockIdx.x * 4 + (threadIdx.x >> 6);
    int lane = threadIdx.x & 63;
    const float* xr = x + (size_t)row * DIMC;
    float v0 = xr[lane], v1 = xr[lane + 64], v2 = xr[lane + 128];
    float s = v0 + v1 + v2;
    float ss = v0 * v0 + v1 * v1 + v2 * v2;
    #pragma unroll
    for (int off = 32; off; off >>= 1) {
        s  += __shfl_xor(s, off);
        ss += __shfl_xor(ss, off);
    }
    float mu  = s * (1.0f / DIMC);
    float var = ss * (1.0f / DIMC) - mu * mu;
    float inv = rsqrtf(var + 1e-5f);
    u16* yr = y + (size_t)row * DIMC;
    yr[lane]       = f2bf((v0 - mu) * inv * g[lane]       + b[lane]);
    yr[lane + 64]  = f2bf((v1 - mu) * inv * g[lane + 64]  + b[lane + 64]);
    yr[lane + 128] = f2bf((v2 - mu) * inv * g[lane + 128] + b[lane + 128]);
}

// ---------------- Weight transpose+convert: W[K][N] f32 -> Wt[N][K] bf16 ---
__global__ __launch_bounds__(256) void wtrans_kernel(const float* w0, const float* w1,
                                                     const float* w2, const float* w3,
                                                     u16* o0, u16* o1, u16* o2, u16* o3) {
    __shared__ float s[16][17];
    int f = blockIdx.x;
    const float* in; u16* out; int K, N, tn, tk;
    if (f < 432)       { in = w0; out = o0; K = 192; N = 576; int r = f;        tn = r % 36; tk = r / 36; }
    else if (f < 576)  { in = w1; out = o1; K = 192; N = 192; int r = f - 432;  tn = r % 12; tk = r / 12; }
    else if (f < 1152) { in = w2; out = o2; K = 192; N = 768; int r = f - 576;  tn = r % 48; tk = r / 48; }
    else               { in = w3; out = o3; K = 768; N = 192; int r = f - 1152; tn = r % 12; tk = r / 12; }
    int tx = threadIdx.x & 15, ty = threadIdx.x >> 4;
    s[ty][tx] = in[(size_t)(tk * 16 + ty) * N + tn * 16 + tx];
    __syncthreads();
    out[(size_t)(tn * 16 + ty) * K + tk * 16 + tx] = f2bf(s[tx][ty]);
}

// ---------------- Bias matrix: bm[h][n][m] = bf16(tab*log2e), 1 idx read ---
__global__ __launch_bounds__(256) void biasmat_kernel(const int* __restrict__ bidx,
                                                      const float* __restrict__ btab,
                                                      int n_off, u16* __restrict__ bm) {
    size_t flat = (size_t)blockIdx.x * 1024 + (size_t)threadIdx.x * 4;
    int4 iv = *(const int4*)(bidx + flat);
    #pragma unroll
    for (int h = 0; h < HEADS; ++h) {
        const float* tab = btab + (size_t)h * n_off;
        ushort4 o;
        o.x = f2bf(tab[iv.x] * L2E);
        o.y = f2bf(tab[iv.y] * L2E);
        o.z = f2bf(tab[iv.z] * L2E);
        o.w = f2bf(tab[iv.w] * L2E);
        *(ushort4*)(bm + (size_t)h * (LTOK * LTOK) + flat) = o;
    }
}

// ---------------- MFMA GEMM: C = act(A@W + bias) (+R)  --------------------
// A bf16 [M][K] row-major, Wt bf16 [N][K]. 256 thr = 4 waves.
// MTILE=128: wave tile 32x64; MTILE=64: wave tile 16x64. K compile-time.
template<int ACT, int RES, int OBF, int QKV, int K, int MTILE>
__global__ __launch_bounds__(256) void gemm_mfma(const u16* __restrict__ A,
                                                 const u16* __restrict__ Wt,
                                                 const float* __restrict__ bias,
                                                 const float* __restrict__ R,
                                                 void* __restrict__ Cp,
                                                 u16* __restrict__ qb,
                                                 u16* __restrict__ kp,
                                                 u16* __restrict__ vp,
                                                 int N) {
    constexpr int SUB = MTILE / 64;          // fragments per wave in M
    int tid = threadIdx.x;
    int L = tid & 63, w = tid >> 6;
    int r = L & 15, g = L >> 4;
    int m0 = blockIdx.y * MTILE + w * (16 * SUB);
    int n0 = blockIdx.x * 64;

    f32x4 acc[SUB][4] = {};
    const u16* Ab = A + (size_t)(m0 + r) * K + g * 8;
    const u16* Wb = Wt + (size_t)(n0 + r) * K + g * 8;
    #pragma unroll 6
    for (int k0 = 0; k0 < K; k0 += 32) {
        s16x8 af[SUB];
        #pragma unroll
        for (int mi = 0; mi < SUB; ++mi)
            af[mi] = *(const s16x8*)(Ab + (size_t)mi * 16 * K + k0);
        #pragma unroll
        for (int nn = 0; nn < 4; ++nn) {
            s16x8 bf = *(const s16x8*)(Wb + (size_t)nn * 16 * K + k0);
            #pragma unroll
            for (int mi = 0; mi < SUB; ++mi)
                acc[mi][nn] = __builtin_amdgcn_mfma_f32_16x16x32_bf16(af[mi], bf, acc[mi][nn], 0, 0, 0);
        }
    }

    #pragma unroll
    for (int mi = 0; mi < SUB; ++mi)
    #pragma unroll
    for (int nn = 0; nn < 4; ++nn) {
        int cb = n0 + nn * 16;
        #pragma unroll
        for (int i = 0; i < 4; ++i) {
            int row = m0 + mi * 16 + g * 4 + i;
            float v = acc[mi][nn][i] + bias[cb + r];
            if (QKV) {
                int h  = cb / 96, c0 = cb % 96;
                int reg = c0 >> 5;               // 0=q, 1=k, 2=v
                if (reg == 0) {
                    v *= QS;
                    qb[(size_t)row * DIMC + h * 32 + (c0 & 31) + r] = f2bf(v);
                } else {
                    int b_ = row / LTOK, t = row - b_ * LTOK;
                    int T = t >> 5, it = t & 31;
                    int d = (c0 & 31) + r;
                    if (reg == 1) {
                        int which = (it >> 2) & 1;
                        int ik = ((it >> 3) << 2) | (it & 3);
                        int Lk = ((d >> 3) << 4) + ik;
                        kp[((size_t)(b_ * HEADS + h) * 40 + T) * 1024 + which * 512 + Lk * 8 + (d & 7)] = f2bf(v);
                    } else {
                        int Lv = ((it >> 3) << 4) + (d & 15);
                        vp[((size_t)(b_ * HEADS + h) * 40 + T) * 1024 + (d >> 4) * 512 + Lv * 8 + (it & 7)] = f2bf(v);
                    }
                }
            } else {
                if (ACT == 1) {
                    float u = v;
                    float y = 0.7978845608028654f * (u + 0.044715f * u * u * u);
                    float e2 = fexp2(y * 2.885390081777927f);   // 2*log2(e)
                    v = u - u * frcp(e2 + 1.0f);                // 0.5u(1+tanh(y))
                }
                if (RES) v += R[(size_t)row * N + cb + r];
                if (OBF) ((u16*)Cp)[(size_t)row * N + cb + r] = f2bf(v);
                else     ((float*)Cp)[(size_t)row * N + cb + r] = v;
            }
        }
    }
}

// ---------------- MFMA flash attention, no-max softmax, split-K=2 ----------
// Block = 4 waves: (qsub 0..1) x (khalf 0..1). Each wave: 20 key-tiles of 32.
__global__ __launch_bounds__(256) void attn_mfma(const u16* __restrict__ qb,
                                                 const u16* __restrict__ kp,
                                                 const u16* __restrict__ vp,
                                                 const u16* __restrict__ bm,
                                                 u16* __restrict__ ob) {
    __shared__ float red[2][64][9];
    int tid = threadIdx.x;
    int L = tid & 63;
    int w = tid >> 6;
    int qsub = w >> 1, kh = w & 1;
    int bx = blockIdx.x;
    int qt = (bx % 40) * 2 + qsub;       // 0..79
    int h  = (bx / 40) % HEADS;
    int b  = bx / (40 * HEADS);
    int r  = L & 15;
    int g  = L >> 4;

    s16x8 qf = *(const s16x8*)(qb + (size_t)(b * LTOK + qt * 16 + r) * DIMC + h * 32 + g * 8);
    const u16* kpt = kp + (size_t)(b * HEADS + h) * 40 * 1024 + (size_t)kh * 20 * 1024 + L * 8;
    const u16* vpt = vp + (size_t)(b * HEADS + h) * 40 * 1024 + (size_t)kh * 20 * 1024 + L * 8;
    const u16* bmr = bm + ((size_t)h * LTOK + qt * 16 + r) * LTOK + (size_t)kh * 20 * 32 + g * 8;

    f32x4 acc0 = {0.f, 0.f, 0.f, 0.f}, acc1 = {0.f, 0.f, 0.f, 0.f};
    float l_run = 0.f;

    #pragma unroll 2
    for (int T = 0; T < 20; ++T) {
        s16x8 kf0 = *(const s16x8*)(kpt + T * 1024);
        s16x8 kf1 = *(const s16x8*)(kpt + T * 1024 + 512);
        int4 bv = *(const int4*)(bmr + T * 32);
        f32x4 z0, z1;
        z0[0] = bflo(bv.x); z0[1] = bfhi(bv.x); z0[2] = bflo(bv.y); z0[3] = bfhi(bv.y);
        z1[0] = bflo(bv.z); z1[1] = bfhi(bv.z); z1[2] = bflo(bv.w); z1[3] = bfhi(bv.w);
        f32x4 s0 = __builtin_amdgcn_mfma_f32_16x16x32_bf16(kf0, qf, z0, 0, 0, 0);
        f32x4 s1 = __builtin_amdgcn_mfma_f32_16x16x32_bf16(kf1, qf, z1, 0, 0, 0);
        float p[8];
        #pragma unroll
        for (int j = 0; j < 4; ++j) p[j] = fexp2(s0[j]);
        #pragma unroll
        for (int j = 0; j < 4; ++j) p[4 + j] = fexp2(s1[j]);
        l_run += ((p[0] + p[1]) + (p[2] + p[3])) + ((p[4] + p[5]) + (p[6] + p[7]));
        union { unsigned u[4]; s16x8 v; } pbu;
        #pragma unroll
        for (int j = 0; j < 4; ++j)
            asm("v_cvt_pk_bf16_f32 %0, %1, %2" : "=v"(pbu.u[j]) : "v"(p[2 * j]), "v"(p[2 * j + 1]));
        s16x8 v0 = *(const s16x8*)(vpt + T * 1024);
        s16x8 v1 = *(const s16x8*)(vpt + T * 1024 + 512);
        acc0 = __builtin_amdgcn_mfma_f32_16x16x32_bf16(pbu.v, v0, acc0, 0, 0, 0);
        acc1 = __builtin_amdgcn_mfma_f32_16x16x32_bf16(pbu.v, v1, acc1, 0, 0, 0);
    }

    if (kh == 1) {
        float* rd = red[qsub][L];
        rd[0] = acc0[0]; rd[1] = acc0[1]; rd[2] = acc0[2]; rd[3] = acc0[3];
        rd[4] = acc1[0]; rd[5] = acc1[1]; rd[6] = acc1[2]; rd[7] = acc1[3];
        rd[8] = l_run;
    }
    __syncthreads();
    if (kh == 0) {
        const float* rd = red[qsub][L];
        acc0[0] += rd[0]; acc0[1] += rd[1]; acc0[2] += rd[2]; acc0[3] += rd[3];
        acc1[0] += rd[4]; acc1[1] += rd[5]; acc1[2] += rd[6]; acc1[3] += rd[7];
        l_run += rd[8];
        l_run += __shfl_xor(l_run, 16);
        l_run += __shfl_xor(l_run, 32);
        #pragma unroll
        for (int i = 0; i < 4; ++i) {
            float linv = frcp(__shfl(l_run, 4 * g + i));
            size_t orow = (size_t)(b * LTOK + qt * 16 + 4 * g + i) * DIMC + h * 32 + r;
            ob[orow]      = f2bf(acc0[i] * linv);
            ob[orow + 16] = f2bf(acc1[i] * linv);
        }
    }
}

// ---------------- Depthwise 3x3 conv + BN, float4 channels -----------------
__global__ __launch_bounds__(256) void conv_bn_kernel(const float* __restrict__ xm,
                                                      const float* __restrict__ w,
                                                      const float* __restrict__ scale,
                                                      const float* __restrict__ bias,
                                                      float* __restrict__ out) {
    int idx = blockIdx.x * 256 + threadIdx.x;   // NROWS*48
    int cc = idx % 48, p = idx / 48;
    int c = cc * 4;
    int b = p / LTOK, t = p - b * LTOK;
    int H, W, base, y, x;
    if (t < 1024) { H = 32; W = 32; base = 0;    y = t >> 5;            x = t & 31; }
    else          { H = 16; W = 16; base = 1024; int tt = t - 1024; y = tt >> 4; x = tt & 15; }
    float4 acc = {0.f, 0.f, 0.f, 0.f};
    #pragma unroll
    for (int ky = 0; ky < 3; ++ky) {
        int yy = y + ky - 1;
        if (yy < 0 || yy >= H) continue;
        #pragma unroll
        for (int kx = 0; kx < 3; ++kx) {
            int xx = x + kx - 1;
            if (xx < 0 || xx >= W) continue;
            float4 wv = *(const float4*)(w + (ky * 3 + kx) * DIMC + c);
            float4 xv = *(const float4*)(xm + (size_t)(b * LTOK + base + yy * W + xx) * DIMC + c);
            acc.x += wv.x * xv.x; acc.y += wv.y * xv.y;
            acc.z += wv.z * xv.z; acc.w += wv.w * xv.w;
        }
    }
    float4 sv = *(const float4*)(scale + c);
    float4 bv = *(const float4*)(bias + c);
    float4 o;
    o.x = acc.x * sv.x + bv.x; o.y = acc.y * sv.y + bv.y;
    o.z = acc.z * sv.z + bv.z; o.w = acc.w * sv.w + bv.w;
    *(float4*)(out + (size_t)(b * LTOK + t) * DIMC + c) = o;
}

// ---------------------------------------------------------------------------
extern "C" void kernel_launch(void* const* d_in, const int* in_sizes, int n_in,
                              void* d_out, int out_size, void* d_ws, size_t ws_size,
                              hipStream_t stream) {
    const float* xz       = (const float*)d_in[0];
    const int*   bidx     = (const int*)  d_in[1];
    const float* ln1_g    = (const float*)d_in[2];
    const float* ln1_b    = (const float*)d_in[3];
    const float* wqkv     = (const float*)d_in[4];
    const float* bqkv     = (const float*)d_in[5];
    const float* wproj    = (const float*)d_in[6];
    const float* bproj    = (const float*)d_in[7];
    const float* btab     = (const float*)d_in[8];
    const float* conv_w   = (const float*)d_in[9];
    const float* bn_scale = (const float*)d_in[10];
    const float* bn_bias  = (const float*)d_in[11];
    const float* ln2_g    = (const float*)d_in[12];
    const float* ln2_b    = (const float*)d_in[13];
    const float* w1       = (const float*)d_in[14];
    const float* b1       = (const float*)d_in[15];
    const float* w2       = (const float*)d_in[16];
    const float* b2       = (const float*)d_in[17];
    int n_off = in_sizes[8] / HEADS;
    float* out = (float*)d_out;

    // ---- workspace layout (bytes), liveness overlays; peak 40.2 MB ----
    char* wsb = (char*)d_ws;
    u16*  hbuf   = (u16*)(wsb + 0);                    // ln out; ob overlays
    u16*  ob     = (u16*)(wsb + 0);
    u16*  wqkvT  = (u16*)(wsb + 3932160);
    u16*  wprojT = (u16*)(wsb + 4153344);
    u16*  w1T    = (u16*)(wsb + 4227072);
    u16*  w2T    = (u16*)(wsb + 4521984);
    u16*  bm     = (u16*)(wsb + 4816896);              // 19.6 MB; hid overlays
    u16*  hid    = (u16*)(wsb + 4816896);
    u16*  kp     = (u16*)(wsb + 24477696);
    u16*  vp     = (u16*)(wsb + 28409856);
    float* xm2   = (float*)(wsb + 24477696);           // overlays kp/vp
    u16*  qb     = (u16*)(wsb + 32342016);
    float* xm    = (float*)(wsb + 32342016);           // overlays qb

    // 1) weight transpose/convert
    wtrans_kernel<<<1728, 256, 0, stream>>>(wqkv, wproj, w1, w2, wqkvT, wprojT, w1T, w2T);
    // 2) bias matrix precompute (exp2 domain), all heads per idx read
    biasmat_kernel<<<LTOK * LTOK / 1024, 256, 0, stream>>>(bidx, btab, n_off, bm);
    // 3) LN1 -> bf16
    ln_kernel<<<NROWS / 4, 256, 0, stream>>>(xz, ln1_g, ln1_b, hbuf);
    // 4) QKV GEMM, scattering q/K/V into attention layouts
    gemm_mfma<0,0,0,1,DIMC,128><<<dim3(576 / 64, NROWS / 128), 256, 0, stream>>>(
        hbuf, wqkvT, bqkv, nullptr, nullptr, qb, kp, vp, 3 * DIMC);
    // 5) attention (split-K=2)
    attn_mfma<<<BATCH * HEADS * 40, 256, 0, stream>>>(qb, kp, vp, bm, ob);
    // 6) proj + residual(xz) -> xm f32
    gemm_mfma<0,1,0,0,DIMC,64><<<dim3(DIMC / 64, NROWS / 64), 256, 0, stream>>>(
        ob, wprojT, bproj, xz, xm, nullptr, nullptr, nullptr, DIMC);
    // 7) depthwise conv + BN -> xm2
    conv_bn_kernel<<<NROWS * 48 / 256, 256, 0, stream>>>(xm, conv_w, bn_scale, bn_bias, xm2);
    // 8) LN2 -> bf16
    ln_kernel<<<NROWS / 4, 256, 0, stream>>>(xm2, ln2_g, ln2_b, hbuf);
    // 9) MLP fc1 + GELU -> hid bf16
    gemm_mfma<1,0,1,0,DIMC,128><<<dim3(HID / 64, NROWS / 128), 256, 0, stream>>>(
        hbuf, w1T, b1, nullptr, hid, nullptr, nullptr, nullptr, HID);
    // 10) MLP fc2 + residual(xm2) -> out f32
    gemm_mfma<0,1,0,0,HID,64><<<dim3(DIMC / 64, NROWS / 64), 256, 0, stream>>>(
        hid, w2T, b2, xm2, out, nullptr, nullptr, nullptr, DIMC);
}

// Round 5
// 156.133 us; speedup vs baseline: 8.6107x; 1.0265x over previous
//
#include <hip/hip_runtime.h>
#include <hip/hip_bf16.h>

#define BATCH 8
#define LTOK 1280
#define DIMC 192
#define HEADS 6
#define KD 32
#define HID 768
#define NROWS (BATCH*LTOK)   // 10240

typedef short s16x8 __attribute__((ext_vector_type(8)));
typedef float f32x4 __attribute__((ext_vector_type(4)));
typedef unsigned short u16;

// q pre-scale: 32^-0.5 * log2(e)  (softmax runs in exp2 domain)
#define QS (0.17677669529663687f * 1.4426950408889634f)
#define L2E 1.4426950408889634f

__device__ __forceinline__ u16 f2bf(float x) {
    unsigned u = __float_as_uint(x);
    u = (u + 0x7FFFu + ((u >> 16) & 1u)) >> 16;
    return (u16)u;
}
__device__ __forceinline__ float bflo(unsigned u) { return __uint_as_float(u << 16); }
__device__ __forceinline__ float bfhi(unsigned u) { return __uint_as_float(u & 0xffff0000u); }
__device__ __forceinline__ float fexp2(float x) { float r; asm("v_exp_f32 %0, %1" : "=v"(r) : "v"(x)); return r; }
__device__ __forceinline__ float frcp(float x)  { float r; asm("v_rcp_f32 %0, %1" : "=v"(r) : "v"(x)); return r; }

// ---------------- LayerNorm -> bf16: 4 rows/block, 64 lanes per row --------
__global__ __launch_bounds__(256) void ln_kernel(const float* __restrict__ x,
                                                 const float* __restrict__ g,
                                                 const float* __restrict__ b,
                                                 u16* __restrict__ y) {
    int row = blockIdx.x * 4 + (threadIdx.x >> 6);
    int lane = threadIdx.x & 63;
    const float* xr = x + (size_t)row * DIMC;
    float v0 = xr[lane], v1 = xr[lane + 64], v2 = xr[lane + 128];
    float s = v0 + v1 + v2;
    float ss = v0 * v0 + v1 * v1 + v2 * v2;
    #pragma unroll
    for (int off = 32; off; off >>= 1) {
        s  += __shfl_xor(s, off);
        ss += __shfl_xor(ss, off);
    }
    float mu  = s * (1.0f / DIMC);
    float var = ss * (1.0f / DIMC) - mu * mu;
    float inv = rsqrtf(var + 1e-5f);
    u16* yr = y + (size_t)row * DIMC;
    yr[lane]       = f2bf((v0 - mu) * inv * g[lane]       + b[lane]);
    yr[lane + 64]  = f2bf((v1 - mu) * inv * g[lane + 64]  + b[lane + 64]);
    yr[lane + 128] = f2bf((v2 - mu) * inv * g[lane + 128] + b[lane + 128]);
}

// ------- Preprocess (merged): weight transpose/convert + bias matrix -------
// blocks [0,1728): W[K][N] f32 -> Wt[N][K] bf16 ; blocks [1728, 3328): bm
__global__ __launch_bounds__(256) void pre_kernel(const float* w0, const float* w1,
                                                  const float* w2, const float* w3,
                                                  u16* o0, u16* o1, u16* o2, u16* o3,
                                                  const int* __restrict__ bidx,
                                                  const float* __restrict__ btab,
                                                  int n_off, u16* __restrict__ bm) {
    __shared__ float s[16][17];
    int f = blockIdx.x;
    if (f >= 1728) {
        size_t flat = (size_t)(f - 1728) * 1024 + (size_t)threadIdx.x * 4;
        int4 iv = *(const int4*)(bidx + flat);
        #pragma unroll
        for (int h = 0; h < HEADS; ++h) {
            const float* tab = btab + (size_t)h * n_off;
            ushort4 o;
            o.x = f2bf(tab[iv.x] * L2E);
            o.y = f2bf(tab[iv.y] * L2E);
            o.z = f2bf(tab[iv.z] * L2E);
            o.w = f2bf(tab[iv.w] * L2E);
            *(ushort4*)(bm + (size_t)h * (LTOK * LTOK) + flat) = o;
        }
        return;
    }
    const float* in; u16* out; int K, N, tn, tk;
    if (f < 432)       { in = w0; out = o0; K = 192; N = 576; int r = f;        tn = r % 36; tk = r / 36; }
    else if (f < 576)  { in = w1; out = o1; K = 192; N = 192; int r = f - 432;  tn = r % 12; tk = r / 12; }
    else if (f < 1152) { in = w2; out = o2; K = 192; N = 768; int r = f - 576;  tn = r % 48; tk = r / 48; }
    else               { in = w3; out = o3; K = 768; N = 192; int r = f - 1152; tn = r % 12; tk = r / 12; }
    int tx = threadIdx.x & 15, ty = threadIdx.x >> 4;
    s[ty][tx] = in[(size_t)(tk * 16 + ty) * N + tn * 16 + tx];
    __syncthreads();
    out[(size_t)(tn * 16 + ty) * K + tk * 16 + tx] = f2bf(s[tx][ty]);
}

// ---------------- MFMA GEMM: C = act(A@W + bias) (+R)  --------------------
// A bf16 [M][K] row-major, Wt bf16 [N][K]. 256 thr = 4 waves.
// MTILE=128: wave tile 32x64; MTILE=64: wave tile 16x64. K compile-time.
template<int ACT, int RES, int OBF, int QKV, int K, int MTILE>
__global__ __launch_bounds__(256) void gemm_mfma(const u16* __restrict__ A,
                                                 const u16* __restrict__ Wt,
                                                 const float* __restrict__ bias,
                                                 const float* __restrict__ R,
                                                 void* __restrict__ Cp,
                                                 u16* __restrict__ qb,
                                                 u16* __restrict__ kp,
                                                 u16* __restrict__ vp,
                                                 int N) {
    constexpr int SUB = MTILE / 64;          // fragments per wave in M
    int tid = threadIdx.x;
    int L = tid & 63, w = tid >> 6;
    int r = L & 15, g = L >> 4;
    int m0 = blockIdx.y * MTILE + w * (16 * SUB);
    int n0 = blockIdx.x * 64;

    f32x4 acc[SUB][4] = {};
    const u16* Ab = A + (size_t)(m0 + r) * K + g * 8;
    const u16* Wb = Wt + (size_t)(n0 + r) * K + g * 8;
    #pragma unroll 6
    for (int k0 = 0; k0 < K; k0 += 32) {
        s16x8 af[SUB];
        #pragma unroll
        for (int mi = 0; mi < SUB; ++mi)
            af[mi] = *(const s16x8*)(Ab + (size_t)mi * 16 * K + k0);
        #pragma unroll
        for (int nn = 0; nn < 4; ++nn) {
            s16x8 bf = *(const s16x8*)(Wb + (size_t)nn * 16 * K + k0);
            #pragma unroll
            for (int mi = 0; mi < SUB; ++mi)
                acc[mi][nn] = __builtin_amdgcn_mfma_f32_16x16x32_bf16(af[mi], bf, acc[mi][nn], 0, 0, 0);
        }
    }

    #pragma unroll
    for (int mi = 0; mi < SUB; ++mi)
    #pragma unroll
    for (int nn = 0; nn < 4; ++nn) {
        int cb = n0 + nn * 16;
        #pragma unroll
        for (int i = 0; i < 4; ++i) {
            int row = m0 + mi * 16 + g * 4 + i;
            float v = acc[mi][nn][i] + bias[cb + r];
            if (QKV) {
                int h  = cb / 96, c0 = cb % 96;
                int reg = c0 >> 5;               // 0=q, 1=k, 2=v
                if (reg == 0) {
                    v *= QS;
                    qb[(size_t)row * DIMC + h * 32 + (c0 & 31) + r] = f2bf(v);
                } else {
                    int b_ = row / LTOK, t = row - b_ * LTOK;
                    int T = t >> 5, it = t & 31;
                    int d = (c0 & 31) + r;
                    if (reg == 1) {
                        int which = (it >> 2) & 1;
                        int ik = ((it >> 3) << 2) | (it & 3);
                        int Lk = ((d >> 3) << 4) + ik;
                        kp[((size_t)(b_ * HEADS + h) * 40 + T) * 1024 + which * 512 + Lk * 8 + (d & 7)] = f2bf(v);
                    } else {
                        int Lv = ((it >> 3) << 4) + (d & 15);
                        vp[((size_t)(b_ * HEADS + h) * 40 + T) * 1024 + (d >> 4) * 512 + Lv * 8 + (it & 7)] = f2bf(v);
                    }
                }
            } else {
                if (ACT == 1) {
                    float u = v;
                    float y = 0.7978845608028654f * (u + 0.044715f * u * u * u);
                    float e2 = fexp2(y * 2.885390081777927f);   // 2*log2(e)
                    v = u - u * frcp(e2 + 1.0f);                // 0.5u(1+tanh(y))
                }
                if (RES) v += R[(size_t)row * N + cb + r];
                if (OBF) ((u16*)Cp)[(size_t)row * N + cb + r] = f2bf(v);
                else     ((float*)Cp)[(size_t)row * N + cb + r] = v;
            }
        }
    }
}

// ---- MFMA flash attention, no-max softmax, split-K=2, batch-pair loop -----
// 960 blocks, chunked-XCD swizzle: work = (bid%8)*120 + bid/8, bp fastest ->
// the 4 batch-pair siblings of one (h,qt-pair) run on one XCD (bm L2-shared).
__global__ __launch_bounds__(256) void attn_mfma(const u16* __restrict__ qb,
                                                 const u16* __restrict__ kp,
                                                 const u16* __restrict__ vp,
                                                 const u16* __restrict__ bm,
                                                 u16* __restrict__ ob) {
    __shared__ float red[2][64][9];
    int tid = threadIdx.x;
    int L = tid & 63;
    int w = tid >> 6;
    int qsub = w >> 1, kh = w & 1;
    int bid = blockIdx.x;
    int work = (bid & 7) * 120 + (bid >> 3);
    int bp  = work & 3;                  // batch pair 0..3
    int qh  = work >> 2;                 // 0..239
    int qtp = qh % 40, h = qh / 40;
    int qt  = qtp * 2 + qsub;            // 0..79
    int r   = L & 15;
    int g   = L >> 4;

    const u16* bmr = bm + ((size_t)h * LTOK + qt * 16 + r) * LTOK + (size_t)kh * 640 + g * 8;

    #pragma unroll
    for (int bi = 0; bi < 2; ++bi) {
        int b = bp * 2 + bi;
        s16x8 qf = *(const s16x8*)(qb + (size_t)(b * LTOK + qt * 16 + r) * DIMC + h * 32 + g * 8);
        const u16* kpt = kp + (size_t)(b * HEADS + h) * 40 * 1024 + (size_t)kh * 20 * 1024 + L * 8;
        const u16* vpt = vp + (size_t)(b * HEADS + h) * 40 * 1024 + (size_t)kh * 20 * 1024 + L * 8;

        f32x4 acc0 = {0.f, 0.f, 0.f, 0.f}, acc1 = {0.f, 0.f, 0.f, 0.f};
        float l_run = 0.f;

        #pragma unroll 2
        for (int T = 0; T < 20; ++T) {
            s16x8 kf0 = *(const s16x8*)(kpt + T * 1024);
            s16x8 kf1 = *(const s16x8*)(kpt + T * 1024 + 512);
            int4 bv = *(const int4*)(bmr + T * 32);
            f32x4 z0, z1;
            z0[0] = bflo(bv.x); z0[1] = bfhi(bv.x); z0[2] = bflo(bv.y); z0[3] = bfhi(bv.y);
            z1[0] = bflo(bv.z); z1[1] = bfhi(bv.z); z1[2] = bflo(bv.w); z1[3] = bfhi(bv.w);
            f32x4 s0 = __builtin_amdgcn_mfma_f32_16x16x32_bf16(kf0, qf, z0, 0, 0, 0);
            f32x4 s1 = __builtin_amdgcn_mfma_f32_16x16x32_bf16(kf1, qf, z1, 0, 0, 0);
            float p[8];
            #pragma unroll
            for (int j = 0; j < 4; ++j) p[j] = fexp2(s0[j]);
            #pragma unroll
            for (int j = 0; j < 4; ++j) p[4 + j] = fexp2(s1[j]);
            l_run += ((p[0] + p[1]) + (p[2] + p[3])) + ((p[4] + p[5]) + (p[6] + p[7]));
            union { unsigned u[4]; s16x8 v; } pbu;
            #pragma unroll
            for (int j = 0; j < 4; ++j)
                asm("v_cvt_pk_bf16_f32 %0, %1, %2" : "=v"(pbu.u[j]) : "v"(p[2 * j]), "v"(p[2 * j + 1]));
            s16x8 v0 = *(const s16x8*)(vpt + T * 1024);
            s16x8 v1 = *(const s16x8*)(vpt + T * 1024 + 512);
            acc0 = __builtin_amdgcn_mfma_f32_16x16x32_bf16(pbu.v, v0, acc0, 0, 0, 0);
            acc1 = __builtin_amdgcn_mfma_f32_16x16x32_bf16(pbu.v, v1, acc1, 0, 0, 0);
        }

        if (kh == 1) {
            float* rd = red[qsub][L];
            rd[0] = acc0[0]; rd[1] = acc0[1]; rd[2] = acc0[2]; rd[3] = acc0[3];
            rd[4] = acc1[0]; rd[5] = acc1[1]; rd[6] = acc1[2]; rd[7] = acc1[3];
            rd[8] = l_run;
        }
        __syncthreads();
        if (kh == 0) {
            const float* rd = red[qsub][L];
            acc0[0] += rd[0]; acc0[1] += rd[1]; acc0[2] += rd[2]; acc0[3] += rd[3];
            acc1[0] += rd[4]; acc1[1] += rd[5]; acc1[2] += rd[6]; acc1[3] += rd[7];
            l_run += rd[8];
            l_run += __shfl_xor(l_run, 16);
            l_run += __shfl_xor(l_run, 32);
            #pragma unroll
            for (int i = 0; i < 4; ++i) {
                float linv = frcp(__shfl(l_run, 4 * g + i));
                size_t orow = (size_t)(b * LTOK + qt * 16 + 4 * g + i) * DIMC + h * 32 + r;
                ob[orow]      = f2bf(acc0[i] * linv);
                ob[orow + 16] = f2bf(acc1[i] * linv);
            }
        }
        __syncthreads();
    }
}

// ---------------- Depthwise 3x3 conv + BN, float4 channels -----------------
__global__ __launch_bounds__(256) void conv_bn_kernel(const float* __restrict__ xm,
                                                      const float* __restrict__ w,
                                                      const float* __restrict__ scale,
                                                      const float* __restrict__ bias,
                                                      float* __restrict__ out) {
    int idx = blockIdx.x * 256 + threadIdx.x;   // NROWS*48
    int cc = idx % 48, p = idx / 48;
    int c = cc * 4;
    int b = p / LTOK, t = p - b * LTOK;
    int H, W, base, y, x;
    if (t < 1024) { H = 32; W = 32; base = 0;    y = t >> 5;            x = t & 31; }
    else          { H = 16; W = 16; base = 1024; int tt = t - 1024; y = tt >> 4; x = tt & 15; }
    float4 acc = {0.f, 0.f, 0.f, 0.f};
    #pragma unroll
    for (int ky = 0; ky < 3; ++ky) {
        int yy = y + ky - 1;
        if (yy < 0 || yy >= H) continue;
        #pragma unroll
        for (int kx = 0; kx < 3; ++kx) {
            int xx = x + kx - 1;
            if (xx < 0 || xx >= W) continue;
            float4 wv = *(const float4*)(w + (ky * 3 + kx) * DIMC + c);
            float4 xv = *(const float4*)(xm + (size_t)(b * LTOK + base + yy * W + xx) * DIMC + c);
            acc.x += wv.x * xv.x; acc.y += wv.y * xv.y;
            acc.z += wv.z * xv.z; acc.w += wv.w * xv.w;
        }
    }
    float4 sv = *(const float4*)(scale + c);
    float4 bv = *(const float4*)(bias + c);
    float4 o;
    o.x = acc.x * sv.x + bv.x; o.y = acc.y * sv.y + bv.y;
    o.z = acc.z * sv.z + bv.z; o.w = acc.w * sv.w + bv.w;
    *(float4*)(out + (size_t)(b * LTOK + t) * DIMC + c) = o;
}

// ---------------------------------------------------------------------------
extern "C" void kernel_launch(void* const* d_in, const int* in_sizes, int n_in,
                              void* d_out, int out_size, void* d_ws, size_t ws_size,
                              hipStream_t stream) {
    const float* xz       = (const float*)d_in[0];
    const int*   bidx     = (const int*)  d_in[1];
    const float* ln1_g    = (const float*)d_in[2];
    const float* ln1_b    = (const float*)d_in[3];
    const float* wqkv     = (const float*)d_in[4];
    const float* bqkv     = (const float*)d_in[5];
    const float* wproj    = (const float*)d_in[6];
    const float* bproj    = (const float*)d_in[7];
    const float* btab     = (const float*)d_in[8];
    const float* conv_w   = (const float*)d_in[9];
    const float* bn_scale = (const float*)d_in[10];
    const float* bn_bias  = (const float*)d_in[11];
    const float* ln2_g    = (const float*)d_in[12];
    const float* ln2_b    = (const float*)d_in[13];
    const float* w1       = (const float*)d_in[14];
    const float* b1       = (const float*)d_in[15];
    const float* w2       = (const float*)d_in[16];
    const float* b2       = (const float*)d_in[17];
    int n_off = in_sizes[8] / HEADS;
    float* out = (float*)d_out;

    // ---- workspace layout (bytes), liveness overlays; peak 40.2 MB ----
    char* wsb = (char*)d_ws;
    u16*  hbuf   = (u16*)(wsb + 0);                    // ln out; ob overlays
    u16*  ob     = (u16*)(wsb + 0);
    u16*  wqkvT  = (u16*)(wsb + 3932160);
    u16*  wprojT = (u16*)(wsb + 4153344);
    u16*  w1T    = (u16*)(wsb + 4227072);
    u16*  w2T    = (u16*)(wsb + 4521984);
    u16*  bm     = (u16*)(wsb + 4816896);              // 19.6 MB; hid overlays
    u16*  hid    = (u16*)(wsb + 4816896);
    u16*  kp     = (u16*)(wsb + 24477696);
    u16*  vp     = (u16*)(wsb + 28409856);
    float* xm2   = (float*)(wsb + 24477696);           // overlays kp/vp
    u16*  qb     = (u16*)(wsb + 32342016);
    float* xm    = (float*)(wsb + 32342016);           // overlays qb

    // 1) preprocess: weight transpose/convert + bias matrix (exp2 domain)
    pre_kernel<<<1728 + LTOK * LTOK / 1024, 256, 0, stream>>>(
        wqkv, wproj, w1, w2, wqkvT, wprojT, w1T, w2T, bidx, btab, n_off, bm);
    // 2) LN1 -> bf16
    ln_kernel<<<NROWS / 4, 256, 0, stream>>>(xz, ln1_g, ln1_b, hbuf);
    // 3) QKV GEMM, scattering q/K/V into attention layouts
    gemm_mfma<0,0,0,1,DIMC,128><<<dim3(576 / 64, NROWS / 128), 256, 0, stream>>>(
        hbuf, wqkvT, bqkv, nullptr, nullptr, qb, kp, vp, 3 * DIMC);
    // 4) attention (split-K=2, batch-pair, XCD-swizzled)
    attn_mfma<<<960, 256, 0, stream>>>(qb, kp, vp, bm, ob);
    // 5) proj + residual(xz) -> xm f32
    gemm_mfma<0,1,0,0,DIMC,64><<<dim3(DIMC / 64, NROWS / 64), 256, 0, stream>>>(
        ob, wprojT, bproj, xz, xm, nullptr, nullptr, nullptr, DIMC);
    // 6) depthwise conv + BN -> xm2
    conv_bn_kernel<<<NROWS * 48 / 256, 256, 0, stream>>>(xm, conv_w, bn_scale, bn_bias, xm2);
    // 7) LN2 -> bf16
    ln_kernel<<<NROWS / 4, 256, 0, stream>>>(xm2, ln2_g, ln2_b, hbuf);
    // 8) MLP fc1 + GELU -> hid bf16
    gemm_mfma<1,0,1,0,DIMC,128><<<dim3(HID / 64, NROWS / 128), 256, 0, stream>>>(
        hbuf, w1T, b1, nullptr, hid, nullptr, nullptr, nullptr, HID);
    // 9) MLP fc2 + residual(xm2) -> out f32
    gemm_mfma<0,1,0,0,HID,64><<<dim3(DIMC / 64, NROWS / 64), 256, 0, stream>>>(
        hid, w2T, b2, xm2, out, nullptr, nullptr, nullptr, DIMC);
}

// Round 6
// 143.409 us; speedup vs baseline: 9.3747x; 1.0887x over previous
//
#include <hip/hip_runtime.h>
#include <hip/hip_bf16.h>

#define BATCH 8
#define LTOK 1280
#define DIMC 192
#define HEADS 6
#define KD 32
#define HID 768
#define NROWS (BATCH*LTOK)   // 10240

typedef short s16x8 __attribute__((ext_vector_type(8)));
typedef float f32x4 __attribute__((ext_vector_type(4)));
typedef unsigned short u16;

// q pre-scale: 32^-0.5 * log2(e)  (softmax runs in exp2 domain)
#define QS (0.17677669529663687f * 1.4426950408889634f)
#define L2E 1.4426950408889634f

__device__ __forceinline__ u16 f2bf(float x) {
    unsigned u = __float_as_uint(x);
    u = (u + 0x7FFFu + ((u >> 16) & 1u)) >> 16;
    return (u16)u;
}
__device__ __forceinline__ float bflo(unsigned u) { return __uint_as_float(u << 16); }
__device__ __forceinline__ float bfhi(unsigned u) { return __uint_as_float(u & 0xffff0000u); }
__device__ __forceinline__ float fexp2(float x) { float r; asm("v_exp_f32 %0, %1" : "=v"(r) : "v"(x)); return r; }
__device__ __forceinline__ float frcp(float x)  { float r; asm("v_rcp_f32 %0, %1" : "=v"(r) : "v"(x)); return r; }

// ---------------- LayerNorm -> bf16: 4 rows/block, 64 lanes per row --------
__global__ __launch_bounds__(256) void ln_kernel(const float* __restrict__ x,
                                                 const float* __restrict__ g,
                                                 const float* __restrict__ b,
                                                 u16* __restrict__ y) {
    int row = blockIdx.x * 4 + (threadIdx.x >> 6);
    int lane = threadIdx.x & 63;
    const float* xr = x + (size_t)row * DIMC;
    float v0 = xr[lane], v1 = xr[lane + 64], v2 = xr[lane + 128];
    float s = v0 + v1 + v2;
    float ss = v0 * v0 + v1 * v1 + v2 * v2;
    #pragma unroll
    for (int off = 32; off; off >>= 1) {
        s  += __shfl_xor(s, off);
        ss += __shfl_xor(ss, off);
    }
    float mu  = s * (1.0f / DIMC);
    float var = ss * (1.0f / DIMC) - mu * mu;
    float inv = rsqrtf(var + 1e-5f);
    u16* yr = y + (size_t)row * DIMC;
    yr[lane]       = f2bf((v0 - mu) * inv * g[lane]       + b[lane]);
    yr[lane + 64]  = f2bf((v1 - mu) * inv * g[lane + 64]  + b[lane + 64]);
    yr[lane + 128] = f2bf((v2 - mu) * inv * g[lane + 128] + b[lane + 128]);
}

// ------- Preprocess (merged): weight transpose/convert + bias matrix -------
// blocks [0,1728): W[K][N] f32 -> Wt[N][K] bf16 ; blocks [1728, 3328): bm
__global__ __launch_bounds__(256) void pre_kernel(const float* w0, const float* w1,
                                                  const float* w2, const float* w3,
                                                  u16* o0, u16* o1, u16* o2, u16* o3,
                                                  const int* __restrict__ bidx,
                                                  const float* __restrict__ btab,
                                                  int n_off, u16* __restrict__ bm) {
    __shared__ float s[16][17];
    int f = blockIdx.x;
    if (f >= 1728) {
        size_t flat = (size_t)(f - 1728) * 1024 + (size_t)threadIdx.x * 4;
        int4 iv = *(const int4*)(bidx + flat);
        #pragma unroll
        for (int h = 0; h < HEADS; ++h) {
            const float* tab = btab + (size_t)h * n_off;
            ushort4 o;
            o.x = f2bf(tab[iv.x] * L2E);
            o.y = f2bf(tab[iv.y] * L2E);
            o.z = f2bf(tab[iv.z] * L2E);
            o.w = f2bf(tab[iv.w] * L2E);
            *(ushort4*)(bm + (size_t)h * (LTOK * LTOK) + flat) = o;
        }
        return;
    }
    const float* in; u16* out; int K, N, tn, tk;
    if (f < 432)       { in = w0; out = o0; K = 192; N = 576; int r = f;        tn = r % 36; tk = r / 36; }
    else if (f < 576)  { in = w1; out = o1; K = 192; N = 192; int r = f - 432;  tn = r % 12; tk = r / 12; }
    else if (f < 1152) { in = w2; out = o2; K = 192; N = 768; int r = f - 576;  tn = r % 48; tk = r / 48; }
    else               { in = w3; out = o3; K = 768; N = 192; int r = f - 1152; tn = r % 12; tk = r / 12; }
    int tx = threadIdx.x & 15, ty = threadIdx.x >> 4;
    s[ty][tx] = in[(size_t)(tk * 16 + ty) * N + tn * 16 + tx];
    __syncthreads();
    out[(size_t)(tn * 16 + ty) * K + tk * 16 + tx] = f2bf(s[tx][ty]);
}

// ---------------- MFMA GEMM: C = act(A@W + bias) (+R)  --------------------
// A bf16 [M][K] row-major, Wt bf16 [N][K]. 256 thr = 4 waves.
// MTILE=128: wave tile 32x64; MTILE=64: wave tile 16x64. K compile-time.
template<int ACT, int RES, int OBF, int QKV, int K, int MTILE>
__global__ __launch_bounds__(256) void gemm_mfma(const u16* __restrict__ A,
                                                 const u16* __restrict__ Wt,
                                                 const float* __restrict__ bias,
                                                 const float* __restrict__ R,
                                                 void* __restrict__ Cp,
                                                 u16* __restrict__ qb,
                                                 u16* __restrict__ kp,
                                                 u16* __restrict__ vp,
                                                 int N) {
    constexpr int SUB = MTILE / 64;          // fragments per wave in M
    int tid = threadIdx.x;
    int L = tid & 63, w = tid >> 6;
    int r = L & 15, g = L >> 4;
    int m0 = blockIdx.y * MTILE + w * (16 * SUB);
    int n0 = blockIdx.x * 64;

    f32x4 acc[SUB][4] = {};
    const u16* Ab = A + (size_t)(m0 + r) * K + g * 8;
    const u16* Wb = Wt + (size_t)(n0 + r) * K + g * 8;
    #pragma unroll 6
    for (int k0 = 0; k0 < K; k0 += 32) {
        s16x8 af[SUB];
        #pragma unroll
        for (int mi = 0; mi < SUB; ++mi)
            af[mi] = *(const s16x8*)(Ab + (size_t)mi * 16 * K + k0);
        #pragma unroll
        for (int nn = 0; nn < 4; ++nn) {
            s16x8 bf = *(const s16x8*)(Wb + (size_t)nn * 16 * K + k0);
            #pragma unroll
            for (int mi = 0; mi < SUB; ++mi)
                acc[mi][nn] = __builtin_amdgcn_mfma_f32_16x16x32_bf16(af[mi], bf, acc[mi][nn], 0, 0, 0);
        }
    }

    #pragma unroll
    for (int mi = 0; mi < SUB; ++mi)
    #pragma unroll
    for (int nn = 0; nn < 4; ++nn) {
        int cb = n0 + nn * 16;
        #pragma unroll
        for (int i = 0; i < 4; ++i) {
            int row = m0 + mi * 16 + g * 4 + i;
            float v = acc[mi][nn][i] + bias[cb + r];
            if (QKV) {
                int h  = cb / 96, c0 = cb % 96;
                int reg = c0 >> 5;               // 0=q, 1=k, 2=v
                if (reg == 0) {
                    v *= QS;
                    qb[(size_t)row * DIMC + h * 32 + (c0 & 31) + r] = f2bf(v);
                } else {
                    int b_ = row / LTOK, t = row - b_ * LTOK;
                    int T = t >> 5, it = t & 31;
                    int d = (c0 & 31) + r;
                    if (reg == 1) {
                        int which = (it >> 2) & 1;
                        int ik = ((it >> 3) << 2) | (it & 3);
                        int Lk = ((d >> 3) << 4) + ik;
                        kp[((size_t)(b_ * HEADS + h) * 40 + T) * 1024 + which * 512 + Lk * 8 + (d & 7)] = f2bf(v);
                    } else {
                        int Lv = ((it >> 3) << 4) + (d & 15);
                        vp[((size_t)(b_ * HEADS + h) * 40 + T) * 1024 + (d >> 4) * 512 + Lv * 8 + (it & 7)] = f2bf(v);
                    }
                }
            } else {
                if (ACT == 1) {
                    float u = v;
                    float y = 0.7978845608028654f * (u + 0.044715f * u * u * u);
                    float e2 = fexp2(y * 2.885390081777927f);   // 2*log2(e)
                    v = u - u * frcp(e2 + 1.0f);                // 0.5u(1+tanh(y))
                }
                if (RES) v += R[(size_t)row * N + cb + r];
                if (OBF) ((u16*)Cp)[(size_t)row * N + cb + r] = f2bf(v);
                else     ((float*)Cp)[(size_t)row * N + cb + r] = v;
            }
        }
    }
}

// ---- MFMA flash attention: LDS-shared K/V, batch-pair, dbuf pipeline ------
// 480 blocks = (bp 4) x (h 6) x (qg 20), XCD-chunk swizzled. 4 waves/block:
// wave w owns q-rows [qg*64 + w*16, +16) for BOTH batches of the pair.
// Per 32-key tile: block stages K+V for both batches (8KB) into LDS
// (reg-staged, double-buffered, 1 barrier/iter); bias is 1 int4/wave/tile,
// prefetched 1 tile ahead, reused across the 2 batches.
__global__ __launch_bounds__(256) void attn_mfma(const u16* __restrict__ qb,
                                                 const u16* __restrict__ kp,
                                                 const u16* __restrict__ vp,
                                                 const u16* __restrict__ bm,
                                                 u16* __restrict__ ob) {
    __shared__ __align__(16) u16 kvs[2][2][2][1024];   // [dbuf][bi][k/v][tile] 16KB
    int tid = threadIdx.x;
    int L = tid & 63, w = tid >> 6;
    int r = L & 15, g = L >> 4;
    int L8 = L * 8;

    int bid = blockIdx.x;
    int work = (bid & 7) * 60 + (bid >> 3);     // XCD-chunk swizzle (480 = 8*60)
    int bp = work & 3;
    int hq = work >> 2;                          // 0..119
    int qt = (hq % 20) * 4 + w;                  // 16-row q-tile, 0..79
    int h  = hq / 20;
    int b0 = bp * 2;

    // q fragments (both batches)
    s16x8 qfr[2];
    qfr[0] = *(const s16x8*)(qb + (size_t)(b0 * LTOK + qt * 16 + r) * DIMC + h * 32 + g * 8);
    qfr[1] = *(const s16x8*)(qb + (size_t)((b0 + 1) * LTOK + qt * 16 + r) * DIMC + h * 32 + g * 8);

    // stage assignment: wave w -> (batch sbi, k/v skv), copies 2KB/tile
    int sbi = w >> 1, skv = w & 1;
    const u16* gsrc = (skv ? vp : kp) + ((size_t)((b0 + sbi) * HEADS + h) * 40) * 1024 + L8;
    u16* lds0 = &kvs[0][sbi][skv][L8];
    u16* lds1 = &kvs[1][sbi][skv][L8];

    const u16* bmr = bm + ((size_t)h * LTOK + qt * 16 + r) * LTOK + g * 8;

    f32x4 acc0[2] = {}, acc1[2] = {};
    float lsum[2] = {0.f, 0.f};

    // prologue: stage tile 0 into buf0, prefetch bias tile 0
    int4 sA = *(const int4*)(gsrc);
    int4 sB = *(const int4*)(gsrc + 512);
    int4 bvn = *(const int4*)(bmr);
    *(int4*)lds0 = sA;
    *(int4*)(lds0 + 512) = sB;
    __syncthreads();

    #pragma unroll 1
    for (int T = 0; T < 40; ++T) {
        int buf = T & 1;
        // issue next tile's global loads early (hidden under compute)
        if (T < 39) {
            sA = *(const int4*)(gsrc + (size_t)(T + 1) * 1024);
            sB = *(const int4*)(gsrc + (size_t)(T + 1) * 1024 + 512);
        }
        int4 bv = bvn;
        if (T < 39) bvn = *(const int4*)(bmr + (size_t)(T + 1) * 32);

        // bias -> C-init (shared by both batches)
        f32x4 z0, z1;
        z0[0] = bflo(bv.x); z0[1] = bfhi(bv.x); z0[2] = bflo(bv.y); z0[3] = bfhi(bv.y);
        z1[0] = bflo(bv.z); z1[1] = bfhi(bv.z); z1[2] = bflo(bv.w); z1[3] = bfhi(bv.w);

        #pragma unroll
        for (int bi = 0; bi < 2; ++bi) {
            s16x8 kf0 = *(const s16x8*)&kvs[buf][bi][0][L8];
            s16x8 kf1 = *(const s16x8*)&kvs[buf][bi][0][512 + L8];
            f32x4 s0 = __builtin_amdgcn_mfma_f32_16x16x32_bf16(kf0, qfr[bi], z0, 0, 0, 0);
            f32x4 s1 = __builtin_amdgcn_mfma_f32_16x16x32_bf16(kf1, qfr[bi], z1, 0, 0, 0);
            float p[8];
            #pragma unroll
            for (int j = 0; j < 4; ++j) p[j] = fexp2(s0[j]);
            #pragma unroll
            for (int j = 0; j < 4; ++j) p[4 + j] = fexp2(s1[j]);
            lsum[bi] += ((p[0] + p[1]) + (p[2] + p[3])) + ((p[4] + p[5]) + (p[6] + p[7]));
            union { unsigned u[4]; s16x8 v; } pbu;
            #pragma unroll
            for (int j = 0; j < 4; ++j)
                asm("v_cvt_pk_bf16_f32 %0, %1, %2" : "=v"(pbu.u[j]) : "v"(p[2 * j]), "v"(p[2 * j + 1]));
            s16x8 v0 = *(const s16x8*)&kvs[buf][bi][1][L8];
            s16x8 v1 = *(const s16x8*)&kvs[buf][bi][1][512 + L8];
            acc0[bi] = __builtin_amdgcn_mfma_f32_16x16x32_bf16(pbu.v, v0, acc0[bi], 0, 0, 0);
            acc1[bi] = __builtin_amdgcn_mfma_f32_16x16x32_bf16(pbu.v, v1, acc1[bi], 0, 0, 0);
        }

        // write next tile into the other buffer (after reads of current)
        if (T < 39) {
            u16* ld = (T & 1) ? lds0 : lds1;
            *(int4*)ld = sA;
            *(int4*)(ld + 512) = sB;
        }
        __syncthreads();
    }

    #pragma unroll
    for (int bi = 0; bi < 2; ++bi) {
        float lr = lsum[bi];
        lr += __shfl_xor(lr, 16);
        lr += __shfl_xor(lr, 32);
        int b = b0 + bi;
        #pragma unroll
        for (int i = 0; i < 4; ++i) {
            float linv = frcp(__shfl(lr, 4 * g + i));
            size_t orow = (size_t)(b * LTOK + qt * 16 + 4 * g + i) * DIMC + h * 32 + r;
            ob[orow]      = f2bf(acc0[bi][i] * linv);
            ob[orow + 16] = f2bf(acc1[bi][i] * linv);
        }
    }
}

// ---------------- Depthwise 3x3 conv + BN, float4 channels -----------------
__global__ __launch_bounds__(256) void conv_bn_kernel(const float* __restrict__ xm,
                                                      const float* __restrict__ w,
                                                      const float* __restrict__ scale,
                                                      const float* __restrict__ bias,
                                                      float* __restrict__ out) {
    int idx = blockIdx.x * 256 + threadIdx.x;   // NROWS*48
    int cc = idx % 48, p = idx / 48;
    int c = cc * 4;
    int b = p / LTOK, t = p - b * LTOK;
    int H, W, base, y, x;
    if (t < 1024) { H = 32; W = 32; base = 0;    y = t >> 5;            x = t & 31; }
    else          { H = 16; W = 16; base = 1024; int tt = t - 1024; y = tt >> 4; x = tt & 15; }
    float4 acc = {0.f, 0.f, 0.f, 0.f};
    #pragma unroll
    for (int ky = 0; ky < 3; ++ky) {
        int yy = y + ky - 1;
        if (yy < 0 || yy >= H) continue;
        #pragma unroll
        for (int kx = 0; kx < 3; ++kx) {
            int xx = x + kx - 1;
            if (xx < 0 || xx >= W) continue;
            float4 wv = *(const float4*)(w + (ky * 3 + kx) * DIMC + c);
            float4 xv = *(const float4*)(xm + (size_t)(b * LTOK + base + yy * W + xx) * DIMC + c);
            acc.x += wv.x * xv.x; acc.y += wv.y * xv.y;
            acc.z += wv.z * xv.z; acc.w += wv.w * xv.w;
        }
    }
    float4 sv = *(const float4*)(scale + c);
    float4 bv = *(const float4*)(bias + c);
    float4 o;
    o.x = acc.x * sv.x + bv.x; o.y = acc.y * sv.y + bv.y;
    o.z = acc.z * sv.z + bv.z; o.w = acc.w * sv.w + bv.w;
    *(float4*)(out + (size_t)(b * LTOK + t) * DIMC + c) = o;
}

// ---------------------------------------------------------------------------
extern "C" void kernel_launch(void* const* d_in, const int* in_sizes, int n_in,
                              void* d_out, int out_size, void* d_ws, size_t ws_size,
                              hipStream_t stream) {
    const float* xz       = (const float*)d_in[0];
    const int*   bidx     = (const int*)  d_in[1];
    const float* ln1_g    = (const float*)d_in[2];
    const float* ln1_b    = (const float*)d_in[3];
    const float* wqkv     = (const float*)d_in[4];
    const float* bqkv     = (const float*)d_in[5];
    const float* wproj    = (const float*)d_in[6];
    const float* bproj    = (const float*)d_in[7];
    const float* btab     = (const float*)d_in[8];
    const float* conv_w   = (const float*)d_in[9];
    const float* bn_scale = (const float*)d_in[10];
    const float* bn_bias  = (const float*)d_in[11];
    const float* ln2_g    = (const float*)d_in[12];
    const float* ln2_b    = (const float*)d_in[13];
    const float* w1       = (const float*)d_in[14];
    const float* b1       = (const float*)d_in[15];
    const float* w2       = (const float*)d_in[16];
    const float* b2       = (const float*)d_in[17];
    int n_off = in_sizes[8] / HEADS;
    float* out = (float*)d_out;

    // ---- workspace layout (bytes), liveness overlays; peak 40.2 MB ----
    char* wsb = (char*)d_ws;
    u16*  hbuf   = (u16*)(wsb + 0);                    // ln out; ob overlays
    u16*  ob     = (u16*)(wsb + 0);
    u16*  wqkvT  = (u16*)(wsb + 3932160);
    u16*  wprojT = (u16*)(wsb + 4153344);
    u16*  w1T    = (u16*)(wsb + 4227072);
    u16*  w2T    = (u16*)(wsb + 4521984);
    u16*  bm     = (u16*)(wsb + 4816896);              // 19.6 MB; hid overlays
    u16*  hid    = (u16*)(wsb + 4816896);
    u16*  kp     = (u16*)(wsb + 24477696);
    u16*  vp     = (u16*)(wsb + 28409856);
    float* xm2   = (float*)(wsb + 24477696);           // overlays kp/vp
    u16*  qb     = (u16*)(wsb + 32342016);
    float* xm    = (float*)(wsb + 32342016);           // overlays qb

    // 1) preprocess: weight transpose/convert + bias matrix (exp2 domain)
    pre_kernel<<<1728 + LTOK * LTOK / 1024, 256, 0, stream>>>(
        wqkv, wproj, w1, w2, wqkvT, wprojT, w1T, w2T, bidx, btab, n_off, bm);
    // 2) LN1 -> bf16
    ln_kernel<<<NROWS / 4, 256, 0, stream>>>(xz, ln1_g, ln1_b, hbuf);
    // 3) QKV GEMM, scattering q/K/V into attention layouts
    gemm_mfma<0,0,0,1,DIMC,128><<<dim3(576 / 64, NROWS / 128), 256, 0, stream>>>(
        hbuf, wqkvT, bqkv, nullptr, nullptr, qb, kp, vp, 3 * DIMC);
    // 4) attention (LDS-shared KV, batch-pair, XCD-swizzled)
    attn_mfma<<<480, 256, 0, stream>>>(qb, kp, vp, bm, ob);
    // 5) proj + residual(xz) -> xm f32
    gemm_mfma<0,1,0,0,DIMC,64><<<dim3(DIMC / 64, NROWS / 64), 256, 0, stream>>>(
        ob, wprojT, bproj, xz, xm, nullptr, nullptr, nullptr, DIMC);
    // 6) depthwise conv + BN -> xm2
    conv_bn_kernel<<<NROWS * 48 / 256, 256, 0, stream>>>(xm, conv_w, bn_scale, bn_bias, xm2);
    // 7) LN2 -> bf16
    ln_kernel<<<NROWS / 4, 256, 0, stream>>>(xm2, ln2_g, ln2_b, hbuf);
    // 8) MLP fc1 + GELU -> hid bf16
    gemm_mfma<1,0,1,0,DIMC,128><<<dim3(HID / 64, NROWS / 128), 256, 0, stream>>>(
        hbuf, w1T, b1, nullptr, hid, nullptr, nullptr, nullptr, HID);
    // 9) MLP fc2 + residual(xm2) -> out f32
    gemm_mfma<0,1,0,0,HID,128><<<dim3(DIMC / 64, NROWS / 128), 256, 0, stream>>>(
        hid, w2T, b2, xm2, out, nullptr, nullptr, nullptr, DIMC);
}